// Round 2
// baseline (751.984 us; speedup 1.0000x reference)
//
#include <hip/hip_runtime.h>

// GlobalInteraction: B=4096, N_GLOBAL=64, D=256, E=4, TPE=16, F=TPE*D=4096
// X:(B,64,256) f32; W1:(E,4096,256); b1:(E,256); W2:(E,256,4096); b2:(E,4096);
// gamma,beta:(E,256). Out:(B,64,256) f32.

typedef __attribute__((ext_vector_type(4))) float f32x4;
typedef __bf16 bf16;
typedef __attribute__((ext_vector_type(8))) bf16 bf16x8;

#define DEV static __device__ __forceinline__

DEV f32x4 zero4() { return f32x4{0.f, 0.f, 0.f, 0.f}; }

// ---------------------------------------------------------------------------
// K0: transpose + cast f32 (R,C) -> bf16 (C,R), per expert (blockIdx.z)
// ---------------------------------------------------------------------------
__global__ void transpose_cast(const float* __restrict__ src,
                               bf16* __restrict__ dst, int R, int C) {
  __shared__ bf16 t[32][33];
  const int e = blockIdx.z;
  const float* s = src + (size_t)e * R * C;
  bf16* d = dst + (size_t)e * R * C;
  const int c0 = blockIdx.x * 32, r0 = blockIdx.y * 32;
  const int tx = threadIdx.x, ty = threadIdx.y;
#pragma unroll
  for (int i = 0; i < 4; i++)
    t[ty + 8 * i][tx] = (bf16)s[(size_t)(r0 + ty + 8 * i) * C + c0 + tx];
  __syncthreads();
#pragma unroll
  for (int i = 0; i < 4; i++)
    d[(size_t)(c0 + ty + 8 * i) * R + r0 + tx] = t[tx][ty + 8 * i];
}

// ---------------------------------------------------------------------------
// K1: attention per (b,e): Y0 = softmax(Xp Xp^T / 16) Xp + Xp
// One wave per pair; writes Y0 as bf16 to ws (useBf) or f32 to Out (fallback).
// ---------------------------------------------------------------------------
__global__ __launch_bounds__(256) void attn_kernel(const float* __restrict__ X,
                                                   float* __restrict__ Y0f,
                                                   bf16* __restrict__ Y0b,
                                                   int useBf) {
  __shared__ __align__(16) bf16 XpT[4][4160];
  __shared__ __align__(16) bf16 Pl[4][512];
  const int tid = threadIdx.x, lane = tid & 63, w = tid >> 6;
  const int lr = lane & 15, g = lane >> 4;
  bf16* xt = XpT[w];
  bf16* pl = Pl[w];

  for (int q = lane; q < 256; q += 64) {        // P cols 16..31 zero
    int row = q >> 4, cc = q & 15;
    pl[row * 32 + 16 + cc] = (bf16)0.f;
  }
  xt[4096 + lane] = (bf16)0.f;

  const int p = blockIdx.x * 4 + w;
  const int b = p >> 2, e = p & 3;
  const float* Xb = X + (size_t)b * 16384 + e * 4096;

  bf16x8 af[8];
#pragma unroll
  for (int c = 0; c < 8; c++) {
    const float* q = Xb + lr * 256 + c * 32 + g * 8;
    f32x4 v0 = *(const f32x4*)q;
    f32x4 v1 = *(const f32x4*)(q + 4);
    bf16x8 o;
    o[0] = (bf16)v0.x; o[1] = (bf16)v0.y; o[2] = (bf16)v0.z; o[3] = (bf16)v0.w;
    o[4] = (bf16)v1.x; o[5] = (bf16)v1.y; o[6] = (bf16)v1.z; o[7] = (bf16)v1.w;
    af[c] = o;
#pragma unroll
    for (int j = 0; j < 8; j++)
      xt[(c * 32 + g * 8 + j) * 16 + lr] = o[j];
  }

  f32x4 s = zero4();
#pragma unroll
  for (int c = 0; c < 8; c++)
    s = __builtin_amdgcn_mfma_f32_16x16x32_bf16(af[c], af[c], s, 0, 0, 0);

  float pv[4];
#pragma unroll
  for (int r = 0; r < 4; r++) {
    float v = s[r] * 0.0625f;
    float mx = v;
#pragma unroll
    for (int m = 1; m < 16; m <<= 1) mx = fmaxf(mx, __shfl_xor(mx, m));
    float ev = __expf(v - mx);
    float sum = ev;
#pragma unroll
    for (int m = 1; m < 16; m <<= 1) sum += __shfl_xor(sum, m);
    pv[r] = ev / sum;
  }
#pragma unroll
  for (int r = 0; r < 4; r++) pl[(g * 4 + r) * 32 + lr] = (bf16)pv[r];

  bf16x8 pf = *(const bf16x8*)&pl[lr * 32 + g * 8];

  const size_t obase0 = (size_t)b * 16384 + e * 4096;
#pragma unroll
  for (int nc = 0; nc < 16; nc++) {
    bf16x8 bfr = *(const bf16x8*)&xt[(nc * 16 + lr) * 16 + g * 8];
    f32x4 xd = __builtin_amdgcn_mfma_f32_16x16x32_bf16(pf, bfr, zero4(), 0, 0, 0);
#pragma unroll
    for (int r = 0; r < 4; r++) {
      int idx = (g * 4 + r) * 256 + nc * 16 + lr;
      float v = xd[r] + Xb[idx];
      if (useBf) Y0b[obase0 + idx] = (bf16)v;
      else       Y0f[obase0 + idx] = v;
    }
  }
}

// ---------------------------------------------------------------------------
// K2: H = relu(Xf @ W1[e] + b1[e]).  M-tile 32, N=256, K=4096 (BK=128).
// 256 threads (4 waves, each owns 64 n-cols). A f32->bf16 via dbuf LDS
// (1 barrier/iter); B-frags straight from global (L2/L3-resident weights).
// ---------------------------------------------------------------------------
__global__ __launch_bounds__(256) void gemm1_kernel(
    const float* __restrict__ X, const bf16* __restrict__ W1T,
    const float* __restrict__ b1, bf16* __restrict__ H) {
  __shared__ __align__(16) bf16 Ab[2][32 * 136];   // [32 rows][128+8 k]
  const int fid = blockIdx.x;                      // expert->XCD swizzle
  const int e = (fid & 7) >> 1;
  const int m = ((fid >> 3) << 1) | (fid & 1);
  const int b0 = m * 32;
  const int tid = threadIdx.x, lane = tid & 63, w = tid >> 6;  // w = wn
  const int lr = lane & 15, g = lane >> 4;

  const float* Xb = X + (size_t)b0 * 16384 + e * 4096;
  const bf16* Wb = W1T + (size_t)e * (256 * 4096);

  const int arow = tid >> 3, ak0 = (tid & 7) * 16;

  f32x4 acc[2][4];
#pragma unroll
  for (int i = 0; i < 2; i++)
#pragma unroll
    for (int j = 0; j < 4; j++) acc[i][j] = zero4();

  f32x4 pv0, pv1, pv2, pv3;
  {
    const float* q = Xb + (size_t)arow * 16384 + ak0;
    pv0 = *(const f32x4*)q;       pv1 = *(const f32x4*)(q + 4);
    pv2 = *(const f32x4*)(q + 8); pv3 = *(const f32x4*)(q + 12);
  }

  for (int kt = 0; kt < 32; kt++) {
    const int cur = kt & 1;
    {  // convert + write LDS
      bf16x8 o0, o1;
      o0[0] = (bf16)pv0.x; o0[1] = (bf16)pv0.y; o0[2] = (bf16)pv0.z; o0[3] = (bf16)pv0.w;
      o0[4] = (bf16)pv1.x; o0[5] = (bf16)pv1.y; o0[6] = (bf16)pv1.z; o0[7] = (bf16)pv1.w;
      o1[0] = (bf16)pv2.x; o1[1] = (bf16)pv2.y; o1[2] = (bf16)pv2.z; o1[3] = (bf16)pv2.w;
      o1[4] = (bf16)pv3.x; o1[5] = (bf16)pv3.y; o1[6] = (bf16)pv3.z; o1[7] = (bf16)pv3.w;
      *(bf16x8*)&Ab[cur][arow * 136 + ak0] = o0;
      *(bf16x8*)&Ab[cur][arow * 136 + ak0 + 8] = o1;
    }
    if (kt < 31) {  // prefetch next A chunk
      const float* q = Xb + (size_t)arow * 16384 + (kt + 1) * 128 + ak0;
      pv0 = *(const f32x4*)q;       pv1 = *(const f32x4*)(q + 4);
      pv2 = *(const f32x4*)(q + 8); pv3 = *(const f32x4*)(q + 12);
    }
    __syncthreads();
#pragma unroll
    for (int kk = 0; kk < 4; kk++) {
      bf16x8 afr[2], bfr[4];
#pragma unroll
      for (int i = 0; i < 2; i++)
        afr[i] = *(const bf16x8*)&Ab[cur][(i * 16 + lr) * 136 + kk * 32 + g * 8];
#pragma unroll
      for (int j = 0; j < 4; j++)
        bfr[j] = *(const bf16x8*)&Wb[(size_t)(w * 64 + j * 16 + lr) * 4096 +
                                     kt * 128 + kk * 32 + g * 8];
#pragma unroll
      for (int i = 0; i < 2; i++)
#pragma unroll
        for (int j = 0; j < 4; j++)
          acc[i][j] = __builtin_amdgcn_mfma_f32_16x16x32_bf16(afr[i], bfr[j],
                                                              acc[i][j], 0, 0, 0);
    }
  }
#pragma unroll
  for (int j = 0; j < 4; j++) {
    int col = w * 64 + j * 16 + lr;
    float bv = b1[e * 256 + col];
#pragma unroll
    for (int i = 0; i < 2; i++)
#pragma unroll
      for (int r = 0; r < 4; r++) {
        int row = i * 16 + g * 4 + r;
        float v = fmaxf(acc[i][j][r] + bv, 0.f);
        H[((size_t)(b0 + row) * 4 + e) * 256 + col] = (bf16)v;
      }
  }
}

// ---------------------------------------------------------------------------
// K3: X_deep = H @ W2[e] + b2; Y = Y0 + X_deep; LayerNorm -> Out (f32)
// M-tile 32, 256 thr (4 waves x 64 n-cols), loop t over 16 token-chunks.
// A-frags preloaded in regs; B-frags from global; no K-loop barriers.
// ---------------------------------------------------------------------------
__global__ __launch_bounds__(256) void gemm2_kernel(
    const bf16* __restrict__ H, const bf16* __restrict__ W2T,
    const float* __restrict__ b2, const float* __restrict__ gamma,
    const float* __restrict__ beta, const float* __restrict__ Y0f,
    const bf16* __restrict__ Y0b, int useBf, float* __restrict__ Out) {
  __shared__ float reds[32 * 4], redq[32 * 4], muL[32], rsL[32];
  const int fid = blockIdx.x;
  const int e = (fid & 7) >> 1;
  const int m = ((fid >> 3) << 1) | (fid & 1);
  const int b0 = m * 32;
  const int tid = threadIdx.x, lane = tid & 63, w = tid >> 6;  // w = wn
  const int lr = lane & 15, g = lane >> 4;

  bf16x8 afr[2][8];
#pragma unroll
  for (int i = 0; i < 2; i++)
#pragma unroll
    for (int c = 0; c < 8; c++)
      afr[i][c] = *(const bf16x8*)&H[((size_t)(b0 + i * 16 + lr) * 4 + e) * 256 +
                                     c * 32 + g * 8];

  float gv[4], btv[4];
#pragma unroll
  for (int j = 0; j < 4; j++) {
    int col = w * 64 + j * 16 + lr;
    gv[j] = gamma[e * 256 + col];
    btv[j] = beta[e * 256 + col];
  }
  const bf16* Wb = W2T + (size_t)e * (4096 * 256);

  for (int t = 0; t < 16; t++) {
    f32x4 acc[2][4];
#pragma unroll
    for (int i = 0; i < 2; i++)
#pragma unroll
      for (int j = 0; j < 4; j++) acc[i][j] = zero4();

#pragma unroll
    for (int c = 0; c < 8; c++) {
      bf16x8 bfr[4];
#pragma unroll
      for (int j = 0; j < 4; j++)
        bfr[j] = *(const bf16x8*)&Wb[(size_t)(t * 256 + w * 64 + j * 16 + lr) * 256 +
                                     c * 32 + g * 8];
#pragma unroll
      for (int i = 0; i < 2; i++)
#pragma unroll
        for (int j = 0; j < 4; j++)
          acc[i][j] = __builtin_amdgcn_mfma_f32_16x16x32_bf16(afr[i][c], bfr[j],
                                                              acc[i][j], 0, 0, 0);
    }

    float b2v[4];
#pragma unroll
    for (int j = 0; j < 4; j++)
      b2v[j] = b2[e * 4096 + t * 256 + w * 64 + j * 16 + lr];

    float y[2][4][4];
#pragma unroll
    for (int i = 0; i < 2; i++)
#pragma unroll
      for (int r = 0; r < 4; r++) {
        int row = i * 16 + g * 4 + r;
        size_t obase = (size_t)(b0 + row) * 16384 + e * 4096 + t * 256;
        float s1 = 0.f, s2 = 0.f;
#pragma unroll
        for (int j = 0; j < 4; j++) {
          int col = w * 64 + j * 16 + lr;
          float y0 = useBf ? (float)Y0b[obase + col] : Y0f[obase + col];
          float v = acc[i][j][r] + b2v[j] + y0;
          y[i][j][r] = v;
          s1 += v;
          s2 += v * v;
        }
#pragma unroll
        for (int mm = 1; mm < 16; mm <<= 1) {
          s1 += __shfl_xor(s1, mm);
          s2 += __shfl_xor(s2, mm);
        }
        if (lr == 0) {
          reds[row * 4 + w] = s1;
          redq[row * 4 + w] = s2;
        }
      }
    __syncthreads();
    if (tid < 32) {
      float s1 = reds[tid * 4] + reds[tid * 4 + 1] + reds[tid * 4 + 2] + reds[tid * 4 + 3];
      float s2 = redq[tid * 4] + redq[tid * 4 + 1] + redq[tid * 4 + 2] + redq[tid * 4 + 3];
      float mu = s1 * (1.f / 256.f);
      float var = s2 * (1.f / 256.f) - mu * mu;
      muL[tid] = mu;
      rsL[tid] = rsqrtf(var + 1e-5f);
    }
    __syncthreads();
#pragma unroll
    for (int i = 0; i < 2; i++)
#pragma unroll
      for (int r = 0; r < 4; r++) {
        int row = i * 16 + g * 4 + r;
        float mu = muL[row], rs = rsL[row];
        size_t obase = (size_t)(b0 + row) * 16384 + e * 4096 + t * 256;
#pragma unroll
        for (int j = 0; j < 4; j++) {
          int col = w * 64 + j * 16 + lr;
          Out[obase + col] = (y[i][j][r] - mu) * rs * gv[j] + btv[j];
        }
      }
  }
}

// ---------------------------------------------------------------------------
extern "C" void kernel_launch(void* const* d_in, const int* in_sizes, int n_in,
                              void* d_out, int out_size, void* d_ws, size_t ws_size,
                              hipStream_t stream) {
  const float* X     = (const float*)d_in[0];
  const float* W1    = (const float*)d_in[1];
  const float* b1    = (const float*)d_in[2];
  const float* W2    = (const float*)d_in[3];
  const float* b2    = (const float*)d_in[4];
  const float* gamma = (const float*)d_in[5];
  const float* beta  = (const float*)d_in[6];
  float* Out = (float*)d_out;

  bf16* W1T = (bf16*)d_ws;                 // (E,256,4096) bf16 : 8 MB
  bf16* W2T = W1T + (size_t)4 * 1048576;   // (E,4096,256) bf16 : 8 MB
  bf16* H   = W2T + (size_t)4 * 1048576;   // (B,E,256)    bf16 : 8 MB
  bf16* Y0b = H + (size_t)4 * 1048576;     // (B,E,4096)   bf16 : 134 MB

  const size_t needBf = (size_t)24 * 1048576 + (size_t)4096 * 64 * 256 * 2;
  const int useBf = (ws_size >= needBf) ? 1 : 0;

  transpose_cast<<<dim3(8, 128, 4), dim3(32, 8), 0, stream>>>(W1, W1T, 4096, 256);
  transpose_cast<<<dim3(128, 8, 4), dim3(32, 8), 0, stream>>>(W2, W2T, 256, 4096);
  attn_kernel<<<dim3(4096), dim3(256), 0, stream>>>(X, Out, Y0b, useBf);
  gemm1_kernel<<<dim3(512), dim3(256), 0, stream>>>(X, W1T, b1, H);
  gemm2_kernel<<<dim3(512), dim3(256), 0, stream>>>(H, W2T, b2, gamma, beta,
                                                    Out, Y0b, useBf, Out);
}

// Round 3
// 529.313 us; speedup vs baseline: 1.4207x; 1.4207x over previous
//
#include <hip/hip_runtime.h>

// GlobalInteraction: B=4096, N_GLOBAL=64, D=256, E=4, TPE=16, F=TPE*D=4096
// X:(B,64,256) f32; W1:(E,4096,256); b1:(E,256); W2:(E,256,4096); b2:(E,4096);
// gamma,beta:(E,256). Out:(B,64,256) f32.
//
// Weights are pre-packed into MFMA B-fragment order: each (16n x 32k) fragment
// stored as 64 lanes x 8 bf16 contiguous (1KB) so a wave's B-load is one
// coalesced global_load_dwordx4 burst. No LDS staging for B, no K-loop
// barriers in gemm2.

typedef __attribute__((ext_vector_type(4))) float f32x4;
typedef __bf16 bf16;
typedef __attribute__((ext_vector_type(8))) bf16 bf16x8;

#define DEV static __device__ __forceinline__

DEV f32x4 zero4() { return f32x4{0.f, 0.f, 0.f, 0.f}; }

DEV bf16x8 cvt8(const f32x4& a, const f32x4& b) {
  bf16x8 o;
  o[0] = (bf16)a.x; o[1] = (bf16)a.y; o[2] = (bf16)a.z; o[3] = (bf16)a.w;
  o[4] = (bf16)b.x; o[5] = (bf16)b.y; o[6] = (bf16)b.z; o[7] = (bf16)b.w;
  return o;
}

// ---------------------------------------------------------------------------
// pack_w1: W1 (E,4096,256) f32 -> fragment-packed bf16.
// Frag (kc,nf): lane l, elem j = W1[e][kc*32+(l>>4)*8+j][nf*16+(l&15)]
// offset = ((e*128+kc)*16+nf)*512 + l*8
// ---------------------------------------------------------------------------
__global__ __launch_bounds__(256) void pack_w1(const float* __restrict__ W1,
                                               bf16* __restrict__ P) {
  const int e = blockIdx.z, kc = blockIdx.y;
  const int nf = blockIdx.x * 4 + (threadIdx.x >> 6);
  const int l = threadIdx.x & 63;
  const float* src = W1 + (size_t)e * 4096 * 256 +
                     (size_t)(kc * 32 + (l >> 4) * 8) * 256 + nf * 16 + (l & 15);
  bf16x8 o;
#pragma unroll
  for (int j = 0; j < 8; j++) o[j] = (bf16)src[(size_t)j * 256];
  *(bf16x8*)&P[(((size_t)e * 128 + kc) * 16 + nf) * 512 + l * 8] = o;
}

// ---------------------------------------------------------------------------
// pack_w2: W2 (E,256,4096) f32 -> fragment-packed bf16.
// Frag (t,nfl,kc): lane l, j = W2[e][kc*32+(l>>4)*8+j][t*256+nfl*16+(l&15)]
// offset = ((e*256 + t*16 + nfl)*8 + kc)*512 + l*8
// ---------------------------------------------------------------------------
__global__ __launch_bounds__(256) void pack_w2(const float* __restrict__ W2,
                                               bf16* __restrict__ P) {
  const int e = blockIdx.z, t = blockIdx.y, kc = blockIdx.x;
  const int l = threadIdx.x & 63;
#pragma unroll
  for (int it = 0; it < 4; it++) {
    int nfl = it * 4 + (threadIdx.x >> 6);
    const float* src = W2 + (size_t)e * 256 * 4096 +
                       (size_t)(kc * 32 + (l >> 4) * 8) * 4096 + t * 256 +
                       nfl * 16 + (l & 15);
    bf16x8 o;
#pragma unroll
    for (int j = 0; j < 8; j++) o[j] = (bf16)src[(size_t)j * 4096];
    *(bf16x8*)&P[(((size_t)e * 256 + t * 16 + nfl) * 8 + kc) * 512 + l * 8] = o;
  }
}

// ---------------------------------------------------------------------------
// attn: per (b,e): Y0 = softmax(Xp Xp^T / 16) Xp + Xp. One wave per pair.
// Also emits Xbf (bf16 cast of X) when useXb, for gemm1's A-staging.
// ---------------------------------------------------------------------------
__global__ __launch_bounds__(256) void attn_kernel(const float* __restrict__ X,
                                                   float* __restrict__ Y0f,
                                                   bf16* __restrict__ Y0b,
                                                   bf16* __restrict__ Xbf,
                                                   int useBf, int useXb) {
  __shared__ __align__(16) bf16 XpT[4][4160];
  __shared__ __align__(16) bf16 Pl[4][512];
  const int tid = threadIdx.x, lane = tid & 63, w = tid >> 6;
  const int lr = lane & 15, g = lane >> 4;
  bf16* xt = XpT[w];
  bf16* pl = Pl[w];

  for (int q = lane; q < 256; q += 64) {  // P cols 16..31 zero
    int row = q >> 4, cc = q & 15;
    pl[row * 32 + 16 + cc] = (bf16)0.f;
  }
  xt[4096 + lane] = (bf16)0.f;

  const int p = blockIdx.x * 4 + w;
  const int b = p >> 2, e = p & 3;
  const size_t obase0 = (size_t)b * 16384 + e * 4096;
  const float* Xb = X + obase0;

  bf16x8 af[8];
#pragma unroll
  for (int c = 0; c < 8; c++) {
    const float* q = Xb + lr * 256 + c * 32 + g * 8;
    f32x4 v0 = *(const f32x4*)q;
    f32x4 v1 = *(const f32x4*)(q + 4);
    bf16x8 o = cvt8(v0, v1);
    af[c] = o;
#pragma unroll
    for (int j = 0; j < 8; j++)
      xt[(c * 32 + g * 8 + j) * 16 + lr] = o[j];
    if (useXb) *(bf16x8*)&Xbf[obase0 + lr * 256 + c * 32 + g * 8] = o;
  }

  f32x4 s = zero4();
#pragma unroll
  for (int c = 0; c < 8; c++)
    s = __builtin_amdgcn_mfma_f32_16x16x32_bf16(af[c], af[c], s, 0, 0, 0);

  float pv[4];
#pragma unroll
  for (int r = 0; r < 4; r++) {
    float v = s[r] * 0.0625f;
    float mx = v;
#pragma unroll
    for (int m = 1; m < 16; m <<= 1) mx = fmaxf(mx, __shfl_xor(mx, m));
    float ev = __expf(v - mx);
    float sum = ev;
#pragma unroll
    for (int m = 1; m < 16; m <<= 1) sum += __shfl_xor(sum, m);
    pv[r] = ev / sum;
  }
#pragma unroll
  for (int r = 0; r < 4; r++) pl[(g * 4 + r) * 32 + lr] = (bf16)pv[r];

  bf16x8 pf = *(const bf16x8*)&pl[lr * 32 + g * 8];

#pragma unroll
  for (int nc = 0; nc < 16; nc++) {
    bf16x8 bfr = *(const bf16x8*)&xt[(nc * 16 + lr) * 16 + g * 8];
    f32x4 xd = __builtin_amdgcn_mfma_f32_16x16x32_bf16(pf, bfr, zero4(), 0, 0, 0);
#pragma unroll
    for (int r = 0; r < 4; r++) {
      int idx = (g * 4 + r) * 256 + nc * 16 + lr;
      float v = xd[r] + Xb[idx];
      if (useBf) Y0b[obase0 + idx] = (bf16)v;
      else       Y0f[obase0 + idx] = v;
    }
  }
}

// ---------------------------------------------------------------------------
// gemm1: H = relu(Xf @ W1[e] + b1[e]).  M-tile 64, N=256, K=4096, BK=128.
// 512 thr (8 waves = 2m x 4n). A reg-staged into padded dbuf LDS; B from
// packed fragments (coalesced global, no LDS).
// ---------------------------------------------------------------------------
template <int USEXBF>
__global__ __launch_bounds__(512) void gemm1_kernel(
    const float* __restrict__ X, const bf16* __restrict__ Xbf,
    const bf16* __restrict__ W1P, const float* __restrict__ b1,
    bf16* __restrict__ H) {
  __shared__ __align__(16) bf16 Ab[2][64 * 136];  // [64 rows][128+8 k]
  const int fid = blockIdx.x;                     // e -> XCD-pair swizzle
  const int e = (fid & 7) >> 1;
  const int m = ((fid >> 3) << 1) | (fid & 1);    // 0..63
  const int b0 = m * 64;
  const int tid = threadIdx.x, lane = tid & 63, w = tid >> 6;
  const int wm = w >> 2, wn = w & 3;
  const int lr = lane & 15, g = lane >> 4;

  const int arow = tid >> 3, ak0 = (tid & 7) * 16;
  const size_t abase = (size_t)(b0 + arow) * 16384 + e * 4096 + ak0;
  const bf16* Wp = W1P + (size_t)e * 128 * 16 * 512;

  f32x4 acc[2][4];
#pragma unroll
  for (int i = 0; i < 2; i++)
#pragma unroll
    for (int j = 0; j < 4; j++) acc[i][j] = zero4();

  f32x4 p0, p1, p2, p3;
  bf16x8 q0, q1;
  if (USEXBF) {
    q0 = *(const bf16x8*)&Xbf[abase];
    q1 = *(const bf16x8*)&Xbf[abase + 8];
  } else {
    const float* q = X + abase;
    p0 = *(const f32x4*)q;       p1 = *(const f32x4*)(q + 4);
    p2 = *(const f32x4*)(q + 8); p3 = *(const f32x4*)(q + 12);
  }

  for (int kt = 0; kt < 32; kt++) {
    const int cur = kt & 1;
    if (USEXBF) {
      *(bf16x8*)&Ab[cur][arow * 136 + ak0] = q0;
      *(bf16x8*)&Ab[cur][arow * 136 + ak0 + 8] = q1;
      if (kt < 31) {
        q0 = *(const bf16x8*)&Xbf[abase + (kt + 1) * 128];
        q1 = *(const bf16x8*)&Xbf[abase + (kt + 1) * 128 + 8];
      }
    } else {
      *(bf16x8*)&Ab[cur][arow * 136 + ak0] = cvt8(p0, p1);
      *(bf16x8*)&Ab[cur][arow * 136 + ak0 + 8] = cvt8(p2, p3);
      if (kt < 31) {
        const float* q = X + abase + (kt + 1) * 128;
        p0 = *(const f32x4*)q;       p1 = *(const f32x4*)(q + 4);
        p2 = *(const f32x4*)(q + 8); p3 = *(const f32x4*)(q + 12);
      }
    }
    __syncthreads();
#pragma unroll
    for (int kki = 0; kki < 4; kki++) {
      const int kc = kt * 4 + kki;
      bf16x8 afr[2], bfr[4];
#pragma unroll
      for (int i = 0; i < 2; i++)
        afr[i] = *(const bf16x8*)&Ab[cur][(wm * 32 + i * 16 + lr) * 136 +
                                          kki * 32 + g * 8];
#pragma unroll
      for (int j = 0; j < 4; j++)
        bfr[j] = *(const bf16x8*)&Wp[(((size_t)kc) * 16 + wn * 4 + j) * 512 +
                                     lane * 8];
#pragma unroll
      for (int i = 0; i < 2; i++)
#pragma unroll
        for (int j = 0; j < 4; j++)
          acc[i][j] = __builtin_amdgcn_mfma_f32_16x16x32_bf16(afr[i], bfr[j],
                                                              acc[i][j], 0, 0, 0);
    }
  }
#pragma unroll
  for (int j = 0; j < 4; j++) {
    int col = wn * 64 + j * 16 + lr;
    float bv = b1[e * 256 + col];
#pragma unroll
    for (int i = 0; i < 2; i++)
#pragma unroll
      for (int r = 0; r < 4; r++) {
        int row = wm * 32 + i * 16 + g * 4 + r;
        float v = fmaxf(acc[i][j][r] + bv, 0.f);
        H[((size_t)(b0 + row) * 4 + e) * 256 + col] = (bf16)v;
      }
  }
}

// ---------------------------------------------------------------------------
// gemm2: X_deep = H @ W2[e] + b2; Y = Y0 + X_deep; LayerNorm -> Out (f32).
// Block = (m-tile 64, token t, e): 64x256 output chunk, K=256, 256 thr
// (4 waves x 64 n-cols). H staged once in LDS; B from packed fragments;
// no K-loop barriers. LN rows complete within the block.
// ---------------------------------------------------------------------------
__global__ __launch_bounds__(256) void gemm2_kernel(
    const bf16* __restrict__ H, const bf16* __restrict__ W2P,
    const float* __restrict__ b2, const float* __restrict__ gamma,
    const float* __restrict__ beta, const float* __restrict__ Y0f,
    const bf16* __restrict__ Y0b, int useBf, float* __restrict__ Out) {
  __shared__ __align__(16) bf16 Ah[64 * 264];  // [64 rows][256+8] (reused for Y0)
  __shared__ float reds[64 * 4], redq[64 * 4], muL[64], rsL[64];
  const int fid = blockIdx.x;
  const int e = (fid & 7) >> 1;
  const int rest = fid >> 3;          // 0..511
  const int t = rest >> 5;            // 0..15
  const int m = ((rest & 31) << 1) | (fid & 1);  // 0..63
  const int b0 = m * 64;
  const int tid = threadIdx.x, lane = tid & 63, w = tid >> 6;
  const int lr = lane & 15, g = lane >> 4;

  // stage H tile (64 x 256 bf16), coalesced
#pragma unroll
  for (int i = 0; i < 8; i++) {
    int u = i * 256 + tid;
    int row = u >> 5, k8 = (u & 31) * 8;
    *(bf16x8*)&Ah[row * 264 + k8] =
        *(const bf16x8*)&H[((size_t)(b0 + row) * 4 + e) * 256 + k8];
  }
  __syncthreads();

  const bf16* Wp = W2P + (((size_t)e * 256 + t * 16 + w * 4) * 8) * 512;

  f32x4 acc[4][4];
#pragma unroll
  for (int i = 0; i < 4; i++)
#pragma unroll
    for (int j = 0; j < 4; j++) acc[i][j] = zero4();

#pragma unroll
  for (int kc = 0; kc < 8; kc++) {
    bf16x8 afr[4], bfr[4];
#pragma unroll
    for (int i = 0; i < 4; i++)
      afr[i] = *(const bf16x8*)&Ah[(i * 16 + lr) * 264 + kc * 32 + g * 8];
#pragma unroll
    for (int j = 0; j < 4; j++)
      bfr[j] = *(const bf16x8*)&Wp[((size_t)j * 8 + kc) * 512 + lane * 8];
#pragma unroll
    for (int i = 0; i < 4; i++)
#pragma unroll
      for (int j = 0; j < 4; j++)
        acc[i][j] = __builtin_amdgcn_mfma_f32_16x16x32_bf16(afr[i], bfr[j],
                                                            acc[i][j], 0, 0, 0);
  }
  __syncthreads();

  // stage Y0 tile into Ah (tier A/B), coalesced
  if (useBf) {
#pragma unroll
    for (int i = 0; i < 8; i++) {
      int u = i * 256 + tid;
      int row = u >> 5, k8 = (u & 31) * 8;
      *(bf16x8*)&Ah[row * 264 + k8] = *(const bf16x8*)
          &Y0b[(size_t)(b0 + row) * 16384 + e * 4096 + t * 256 + k8];
    }
  }
  __syncthreads();

  float b2v[4], gv[4], btv[4];
#pragma unroll
  for (int j = 0; j < 4; j++) {
    int col = w * 64 + j * 16 + lr;
    b2v[j] = b2[e * 4096 + t * 256 + col];
    gv[j] = gamma[e * 256 + col];
    btv[j] = beta[e * 256 + col];
  }

#pragma unroll
  for (int i = 0; i < 4; i++)
#pragma unroll
    for (int r = 0; r < 4; r++) {
      int row = i * 16 + g * 4 + r;
      size_t obase = (size_t)(b0 + row) * 16384 + e * 4096 + t * 256;
      float s1 = 0.f, s2 = 0.f;
#pragma unroll
      for (int j = 0; j < 4; j++) {
        int col = w * 64 + j * 16 + lr;
        float y0 = useBf ? (float)Ah[row * 264 + col] : Y0f[obase + col];
        float v = acc[i][j][r] + b2v[j] + y0;
        acc[i][j][r] = v;
        s1 += v;
        s2 += v * v;
      }
#pragma unroll
      for (int mm = 1; mm < 16; mm <<= 1) {
        s1 += __shfl_xor(s1, mm);
        s2 += __shfl_xor(s2, mm);
      }
      if (lr == 0) {
        reds[row * 4 + w] = s1;
        redq[row * 4 + w] = s2;
      }
    }
  __syncthreads();
  if (tid < 64) {
    float s1 = reds[tid * 4] + reds[tid * 4 + 1] + reds[tid * 4 + 2] + reds[tid * 4 + 3];
    float s2 = redq[tid * 4] + redq[tid * 4 + 1] + redq[tid * 4 + 2] + redq[tid * 4 + 3];
    float mu = s1 * (1.f / 256.f);
    float var = s2 * (1.f / 256.f) - mu * mu;
    muL[tid] = mu;
    rsL[tid] = rsqrtf(var + 1e-5f);
  }
  __syncthreads();
#pragma unroll
  for (int i = 0; i < 4; i++)
#pragma unroll
    for (int r = 0; r < 4; r++) {
      int row = i * 16 + g * 4 + r;
      float mu = muL[row], rs = rsL[row];
      size_t obase = (size_t)(b0 + row) * 16384 + e * 4096 + t * 256;
#pragma unroll
      for (int j = 0; j < 4; j++) {
        int col = w * 64 + j * 16 + lr;
        Out[obase + col] = (acc[i][j][r] - mu) * rs * gv[j] + btv[j];
      }
    }
}

// ---------------------------------------------------------------------------
extern "C" void kernel_launch(void* const* d_in, const int* in_sizes, int n_in,
                              void* d_out, int out_size, void* d_ws, size_t ws_size,
                              hipStream_t stream) {
  const float* X     = (const float*)d_in[0];
  const float* W1    = (const float*)d_in[1];
  const float* b1    = (const float*)d_in[2];
  const float* W2    = (const float*)d_in[3];
  const float* b2    = (const float*)d_in[4];
  const float* gamma = (const float*)d_in[5];
  const float* beta  = (const float*)d_in[6];
  float* Out = (float*)d_out;

  const size_t MB8 = (size_t)4 * 1048576;        // 4M bf16 elems = 8 MB
  bf16* W1P = (bf16*)d_ws;                       // 8 MB
  bf16* W2P = W1P + MB8;                         // 8 MB
  bf16* H   = W2P + MB8;                         // 8 MB
  bf16* Y0b = H + MB8;                           // 134 MB
  bf16* Xbf = Y0b + (size_t)4096 * 16384;        // 134 MB

  const size_t bigN = (size_t)4096 * 16384 * 2;  // 134,217,728 B
  const size_t base = 3 * (MB8 * 2);             // 25,165,824 B
  const int useBf = (ws_size >= base + bigN) ? 1 : 0;
  const int useXb = (ws_size >= base + 2 * bigN) ? 1 : 0;

  pack_w1<<<dim3(4, 128, 4), dim3(256), 0, stream>>>(W1, W1P);
  pack_w2<<<dim3(8, 16, 4), dim3(256), 0, stream>>>(W2, W2P);
  attn_kernel<<<dim3(4096), dim3(256), 0, stream>>>(X, Out, Y0b, Xbf, useBf, useXb);
  if (useXb)
    gemm1_kernel<1><<<dim3(256), dim3(512), 0, stream>>>(X, Xbf, W1P, b1, H);
  else
    gemm1_kernel<0><<<dim3(256), dim3(512), 0, stream>>>(X, Xbf, W1P, b1, H);
  gemm2_kernel<<<dim3(4096), dim3(256), 0, stream>>>(H, W2P, b2, gamma, beta,
                                                     Out, Y0b, useBf, Out);
}

// Round 4
// 450.588 us; speedup vs baseline: 1.6689x; 1.1747x over previous
//
#include <hip/hip_runtime.h>

// GlobalInteraction: B=4096, N_GLOBAL=64, D=256, E=4, TPE=16, F=TPE*D=4096
// X:(B,64,256) f32; W1:(E,4096,256); b1:(E,256); W2:(E,256,4096); b2:(E,4096);
// gamma,beta:(E,256). Out:(B,64,256) f32.
//
// Weights pre-packed into MFMA B-fragment order (64 lanes x 8 bf16 = 1KB per
// 16n x 32k fragment) -> coalesced B loads, no B LDS staging, no K barriers
// in gemm2. attn: per-wave 16x16 attention; PV accumulated in registers,
// output transposed through LDS (reusing XpT) for full-line bf16x8 stores.

typedef __attribute__((ext_vector_type(4))) float f32x4;
typedef __bf16 bf16;
typedef __attribute__((ext_vector_type(8))) bf16 bf16x8;

#define DEV static __device__ __forceinline__

DEV f32x4 zero4() { return f32x4{0.f, 0.f, 0.f, 0.f}; }

DEV bf16x8 cvt8(const f32x4& a, const f32x4& b) {
  bf16x8 o;
  o[0] = (bf16)a.x; o[1] = (bf16)a.y; o[2] = (bf16)a.z; o[3] = (bf16)a.w;
  o[4] = (bf16)b.x; o[5] = (bf16)b.y; o[6] = (bf16)b.z; o[7] = (bf16)b.w;
  return o;
}

// ---------------------------------------------------------------------------
// pack_w1: W1 (E,4096,256) f32 -> fragment-packed bf16.
// Frag (kc,nf): lane l, elem j = W1[e][kc*32+(l>>4)*8+j][nf*16+(l&15)]
// offset = ((e*128+kc)*16+nf)*512 + l*8
// ---------------------------------------------------------------------------
__global__ __launch_bounds__(256) void pack_w1(const float* __restrict__ W1,
                                               bf16* __restrict__ P) {
  const int e = blockIdx.z, kc = blockIdx.y;
  const int nf = blockIdx.x * 4 + (threadIdx.x >> 6);
  const int l = threadIdx.x & 63;
  const float* src = W1 + (size_t)e * 4096 * 256 +
                     (size_t)(kc * 32 + (l >> 4) * 8) * 256 + nf * 16 + (l & 15);
  bf16x8 o;
#pragma unroll
  for (int j = 0; j < 8; j++) o[j] = (bf16)src[(size_t)j * 256];
  *(bf16x8*)&P[(((size_t)e * 128 + kc) * 16 + nf) * 512 + l * 8] = o;
}

// ---------------------------------------------------------------------------
// pack_w2: W2 (E,256,4096) f32 -> fragment-packed bf16.
// Frag (t,nfl,kc): lane l, j = W2[e][kc*32+(l>>4)*8+j][t*256+nfl*16+(l&15)]
// offset = ((e*256 + t*16 + nfl)*8 + kc)*512 + l*8
// ---------------------------------------------------------------------------
__global__ __launch_bounds__(256) void pack_w2(const float* __restrict__ W2,
                                               bf16* __restrict__ P) {
  const int e = blockIdx.z, t = blockIdx.y, kc = blockIdx.x;
  const int l = threadIdx.x & 63;
#pragma unroll
  for (int it = 0; it < 4; it++) {
    int nfl = it * 4 + (threadIdx.x >> 6);
    const float* src = W2 + (size_t)e * 256 * 4096 +
                       (size_t)(kc * 32 + (l >> 4) * 8) * 4096 + t * 256 +
                       nfl * 16 + (l & 15);
    bf16x8 o;
#pragma unroll
    for (int j = 0; j < 8; j++) o[j] = (bf16)src[(size_t)j * 4096];
    *(bf16x8*)&P[(((size_t)e * 256 + t * 16 + nfl) * 8 + kc) * 512 + l * 8] = o;
  }
}

// ---------------------------------------------------------------------------
// attn: per (b,e): Y0 = softmax(Xp Xp^T / 16) Xp + Xp. One wave per pair.
// Also emits Xbf (bf16 cast of X) when useXb, for gemm1's A-staging.
// PV output accumulated in regs, transposed via LDS (XpT reuse), stored as
// full-line bf16x8.
// ---------------------------------------------------------------------------
__global__ __launch_bounds__(256) void attn_kernel(const float* __restrict__ X,
                                                   float* __restrict__ Y0f,
                                                   bf16* __restrict__ Y0b,
                                                   bf16* __restrict__ Xbf,
                                                   int useBf, int useXb) {
  // XpT: [d=256][tok=16] stride 16 (+pad); reused post-PV as Yl[16][264]
  __shared__ __align__(16) bf16 XpT[4][4224];
  __shared__ __align__(16) bf16 Pl[4][512];
  const int tid = threadIdx.x, lane = tid & 63, w = tid >> 6;
  const int lr = lane & 15, g = lane >> 4;
  bf16* xt = XpT[w];
  bf16* pl = Pl[w];

  for (int q = lane; q < 256; q += 64) {  // P cols 16..31 zero
    int row = q >> 4, cc = q & 15;
    pl[row * 32 + 16 + cc] = (bf16)0.f;
  }
  xt[4096 + lane] = (bf16)0.f;  // zero pad region [4096,4160)

  const int p = blockIdx.x * 4 + w;
  const int b = p >> 2, e = p & 3;
  const size_t obase0 = (size_t)b * 16384 + e * 4096;
  const float* Xb = X + obase0;

  bf16x8 af[8];
#pragma unroll
  for (int c = 0; c < 8; c++) {
    const float* q = Xb + lr * 256 + c * 32 + g * 8;
    f32x4 v0 = *(const f32x4*)q;
    f32x4 v1 = *(const f32x4*)(q + 4);
    bf16x8 o = cvt8(v0, v1);
    af[c] = o;
#pragma unroll
    for (int j = 0; j < 8; j++)
      xt[(c * 32 + g * 8 + j) * 16 + lr] = o[j];
    if (useXb) *(bf16x8*)&Xbf[obase0 + lr * 256 + c * 32 + g * 8] = o;
  }

  f32x4 s = zero4();
#pragma unroll
  for (int c = 0; c < 8; c++)
    s = __builtin_amdgcn_mfma_f32_16x16x32_bf16(af[c], af[c], s, 0, 0, 0);

  float pv[4];
#pragma unroll
  for (int r = 0; r < 4; r++) {
    float v = s[r] * 0.0625f;
    float mx = v;
#pragma unroll
    for (int m = 1; m < 16; m <<= 1) mx = fmaxf(mx, __shfl_xor(mx, m));
    float ev = __expf(v - mx);
    float sum = ev;
#pragma unroll
    for (int m = 1; m < 16; m <<= 1) sum += __shfl_xor(sum, m);
    pv[r] = ev / sum;
  }
#pragma unroll
  for (int r = 0; r < 4; r++) pl[(g * 4 + r) * 32 + lr] = (bf16)pv[r];

  bf16x8 pf = *(const bf16x8*)&pl[lr * 32 + g * 8];

  // PV: accumulate X_dot + Xp in registers (lane: tok=g*4+r, d=nc*16+lr)
  float yo[16][4];
#pragma unroll
  for (int nc = 0; nc < 16; nc++) {
    bf16x8 bfr = *(const bf16x8*)&xt[(nc * 16 + lr) * 16 + g * 8];
    f32x4 xd = __builtin_amdgcn_mfma_f32_16x16x32_bf16(pf, bfr, zero4(), 0, 0, 0);
#pragma unroll
    for (int r = 0; r < 4; r++)
      yo[nc][r] = xd[r] + (float)xt[(nc * 16 + lr) * 16 + g * 4 + r];
  }

  // transpose via LDS: Yl[tok][264] overlays xt (all xt reads complete; same
  // wave -> lgkmcnt orders the aliasing)
#pragma unroll
  for (int nc = 0; nc < 16; nc++)
#pragma unroll
    for (int r = 0; r < 4; r++)
      xt[(g * 4 + r) * 264 + nc * 16 + lr] = (bf16)yo[nc][r];

  // coalesced store: instr i writes 16 full 64B lines
  const int tok = lane >> 2, cc = lane & 3;
  if (useBf) {
#pragma unroll
    for (int i = 0; i < 8; i++) {
      int d0 = i * 32 + cc * 8;
      bf16x8 v = *(const bf16x8*)&xt[tok * 264 + d0];
      *(bf16x8*)&Y0b[obase0 + tok * 256 + d0] = v;
    }
  } else {
#pragma unroll
    for (int i = 0; i < 8; i++) {
      int d0 = i * 32 + cc * 8;
      bf16x8 v = *(const bf16x8*)&xt[tok * 264 + d0];
      f32x4 a, bb;
      a.x = (float)v[0]; a.y = (float)v[1]; a.z = (float)v[2]; a.w = (float)v[3];
      bb.x = (float)v[4]; bb.y = (float)v[5]; bb.z = (float)v[6]; bb.w = (float)v[7];
      *(f32x4*)&Y0f[obase0 + tok * 256 + d0] = a;
      *(f32x4*)&Y0f[obase0 + tok * 256 + d0 + 4] = bb;
    }
  }
}

// ---------------------------------------------------------------------------
// gemm1: H = relu(Xf @ W1[e] + b1[e]).  M-tile 64, N=256, K=4096, BK=128.
// 512 thr (8 waves = 2m x 4n). A reg-staged into padded dbuf LDS; B from
// packed fragments (coalesced global, no LDS).
// ---------------------------------------------------------------------------
template <int USEXBF>
__global__ __launch_bounds__(512) void gemm1_kernel(
    const float* __restrict__ X, const bf16* __restrict__ Xbf,
    const bf16* __restrict__ W1P, const float* __restrict__ b1,
    bf16* __restrict__ H) {
  __shared__ __align__(16) bf16 Ab[2][64 * 136];  // [64 rows][128+8 k]
  const int fid = blockIdx.x;                     // e -> XCD-pair swizzle
  const int e = (fid & 7) >> 1;
  const int m = ((fid >> 3) << 1) | (fid & 1);    // 0..63
  const int b0 = m * 64;
  const int tid = threadIdx.x, lane = tid & 63, w = tid >> 6;
  const int wm = w >> 2, wn = w & 3;
  const int lr = lane & 15, g = lane >> 4;

  const int arow = tid >> 3, ak0 = (tid & 7) * 16;
  const size_t abase = (size_t)(b0 + arow) * 16384 + e * 4096 + ak0;
  const bf16* Wp = W1P + (size_t)e * 128 * 16 * 512;

  f32x4 acc[2][4];
#pragma unroll
  for (int i = 0; i < 2; i++)
#pragma unroll
    for (int j = 0; j < 4; j++) acc[i][j] = zero4();

  f32x4 p0, p1, p2, p3;
  bf16x8 q0, q1;
  if (USEXBF) {
    q0 = *(const bf16x8*)&Xbf[abase];
    q1 = *(const bf16x8*)&Xbf[abase + 8];
  } else {
    const float* q = X + abase;
    p0 = *(const f32x4*)q;       p1 = *(const f32x4*)(q + 4);
    p2 = *(const f32x4*)(q + 8); p3 = *(const f32x4*)(q + 12);
  }

  for (int kt = 0; kt < 32; kt++) {
    const int cur = kt & 1;
    if (USEXBF) {
      *(bf16x8*)&Ab[cur][arow * 136 + ak0] = q0;
      *(bf16x8*)&Ab[cur][arow * 136 + ak0 + 8] = q1;
      if (kt < 31) {
        q0 = *(const bf16x8*)&Xbf[abase + (kt + 1) * 128];
        q1 = *(const bf16x8*)&Xbf[abase + (kt + 1) * 128 + 8];
      }
    } else {
      *(bf16x8*)&Ab[cur][arow * 136 + ak0] = cvt8(p0, p1);
      *(bf16x8*)&Ab[cur][arow * 136 + ak0 + 8] = cvt8(p2, p3);
      if (kt < 31) {
        const float* q = X + abase + (kt + 1) * 128;
        p0 = *(const f32x4*)q;       p1 = *(const f32x4*)(q + 4);
        p2 = *(const f32x4*)(q + 8); p3 = *(const f32x4*)(q + 12);
      }
    }
    __syncthreads();
#pragma unroll
    for (int kki = 0; kki < 4; kki++) {
      const int kc = kt * 4 + kki;
      bf16x8 afr[2], bfr[4];
#pragma unroll
      for (int i = 0; i < 2; i++)
        afr[i] = *(const bf16x8*)&Ab[cur][(wm * 32 + i * 16 + lr) * 136 +
                                          kki * 32 + g * 8];
#pragma unroll
      for (int j = 0; j < 4; j++)
        bfr[j] = *(const bf16x8*)&Wp[(((size_t)kc) * 16 + wn * 4 + j) * 512 +
                                     lane * 8];
#pragma unroll
      for (int i = 0; i < 2; i++)
#pragma unroll
        for (int j = 0; j < 4; j++)
          acc[i][j] = __builtin_amdgcn_mfma_f32_16x16x32_bf16(afr[i], bfr[j],
                                                              acc[i][j], 0, 0, 0);
    }
  }
#pragma unroll
  for (int j = 0; j < 4; j++) {
    int col = wn * 64 + j * 16 + lr;
    float bv = b1[e * 256 + col];
#pragma unroll
    for (int i = 0; i < 2; i++)
#pragma unroll
      for (int r = 0; r < 4; r++) {
        int row = wm * 32 + i * 16 + g * 4 + r;
        float v = fmaxf(acc[i][j][r] + bv, 0.f);
        H[((size_t)(b0 + row) * 4 + e) * 256 + col] = (bf16)v;
      }
  }
}

// ---------------------------------------------------------------------------
// gemm2: X_deep = H @ W2[e] + b2; Y = Y0 + X_deep; LayerNorm -> Out (f32).
// Block = (m-tile 64, token t, e): 64x256 output chunk, K=256, 256 thr
// (4 waves x 64 n-cols). H staged once in LDS; B from packed fragments;
// no K-loop barriers. LN rows complete within the block.
// ---------------------------------------------------------------------------
__global__ __launch_bounds__(256) void gemm2_kernel(
    const bf16* __restrict__ H, const bf16* __restrict__ W2P,
    const float* __restrict__ b2, const float* __restrict__ gamma,
    const float* __restrict__ beta, const float* __restrict__ Y0f,
    const bf16* __restrict__ Y0b, int useBf, float* __restrict__ Out) {
  __shared__ __align__(16) bf16 Ah[64 * 264];  // [64 rows][256+8] (reused for Y0)
  __shared__ float reds[64 * 4], redq[64 * 4], muL[64], rsL[64];
  const int fid = blockIdx.x;
  const int e = (fid & 7) >> 1;
  const int rest = fid >> 3;          // 0..511
  const int t = rest >> 5;            // 0..15
  const int m = ((rest & 31) << 1) | (fid & 1);  // 0..63
  const int b0 = m * 64;
  const int tid = threadIdx.x, lane = tid & 63, w = tid >> 6;
  const int lr = lane & 15, g = lane >> 4;

  // stage H tile (64 x 256 bf16), coalesced
#pragma unroll
  for (int i = 0; i < 8; i++) {
    int u = i * 256 + tid;
    int row = u >> 5, k8 = (u & 31) * 8;
    *(bf16x8*)&Ah[row * 264 + k8] =
        *(const bf16x8*)&H[((size_t)(b0 + row) * 4 + e) * 256 + k8];
  }
  __syncthreads();

  const bf16* Wp = W2P + (((size_t)e * 256 + t * 16 + w * 4) * 8) * 512;

  f32x4 acc[4][4];
#pragma unroll
  for (int i = 0; i < 4; i++)
#pragma unroll
    for (int j = 0; j < 4; j++) acc[i][j] = zero4();

#pragma unroll
  for (int kc = 0; kc < 8; kc++) {
    bf16x8 afr[4], bfr[4];
#pragma unroll
    for (int i = 0; i < 4; i++)
      afr[i] = *(const bf16x8*)&Ah[(i * 16 + lr) * 264 + kc * 32 + g * 8];
#pragma unroll
    for (int j = 0; j < 4; j++)
      bfr[j] = *(const bf16x8*)&Wp[((size_t)j * 8 + kc) * 512 + lane * 8];
#pragma unroll
    for (int i = 0; i < 4; i++)
#pragma unroll
      for (int j = 0; j < 4; j++)
        acc[i][j] = __builtin_amdgcn_mfma_f32_16x16x32_bf16(afr[i], bfr[j],
                                                            acc[i][j], 0, 0, 0);
  }
  __syncthreads();

  // stage Y0 tile into Ah (tier A/B), coalesced
  if (useBf) {
#pragma unroll
    for (int i = 0; i < 8; i++) {
      int u = i * 256 + tid;
      int row = u >> 5, k8 = (u & 31) * 8;
      *(bf16x8*)&Ah[row * 264 + k8] = *(const bf16x8*)
          &Y0b[(size_t)(b0 + row) * 16384 + e * 4096 + t * 256 + k8];
    }
  }
  __syncthreads();

  float b2v[4], gv[4], btv[4];
#pragma unroll
  for (int j = 0; j < 4; j++) {
    int col = w * 64 + j * 16 + lr;
    b2v[j] = b2[e * 4096 + t * 256 + col];
    gv[j] = gamma[e * 256 + col];
    btv[j] = beta[e * 256 + col];
  }

#pragma unroll
  for (int i = 0; i < 4; i++)
#pragma unroll
    for (int r = 0; r < 4; r++) {
      int row = i * 16 + g * 4 + r;
      size_t obase = (size_t)(b0 + row) * 16384 + e * 4096 + t * 256;
      float s1 = 0.f, s2 = 0.f;
#pragma unroll
      for (int j = 0; j < 4; j++) {
        int col = w * 64 + j * 16 + lr;
        float y0 = useBf ? (float)Ah[row * 264 + col] : Y0f[obase + col];
        float v = acc[i][j][r] + b2v[j] + y0;
        acc[i][j][r] = v;
        s1 += v;
        s2 += v * v;
      }
#pragma unroll
      for (int mm = 1; mm < 16; mm <<= 1) {
        s1 += __shfl_xor(s1, mm);
        s2 += __shfl_xor(s2, mm);
      }
      if (lr == 0) {
        reds[row * 4 + w] = s1;
        redq[row * 4 + w] = s2;
      }
    }
  __syncthreads();
  if (tid < 64) {
    float s1 = reds[tid * 4] + reds[tid * 4 + 1] + reds[tid * 4 + 2] + reds[tid * 4 + 3];
    float s2 = redq[tid * 4] + redq[tid * 4 + 1] + redq[tid * 4 + 2] + redq[tid * 4 + 3];
    float mu = s1 * (1.f / 256.f);
    float var = s2 * (1.f / 256.f) - mu * mu;
    muL[tid] = mu;
    rsL[tid] = rsqrtf(var + 1e-5f);
  }
  __syncthreads();
#pragma unroll
  for (int i = 0; i < 4; i++)
#pragma unroll
    for (int r = 0; r < 4; r++) {
      int row = i * 16 + g * 4 + r;
      float mu = muL[row], rs = rsL[row];
      size_t obase = (size_t)(b0 + row) * 16384 + e * 4096 + t * 256;
#pragma unroll
      for (int j = 0; j < 4; j++) {
        int col = w * 64 + j * 16 + lr;
        Out[obase + col] = (acc[i][j][r] - mu) * rs * gv[j] + btv[j];
      }
    }
}

// ---------------------------------------------------------------------------
extern "C" void kernel_launch(void* const* d_in, const int* in_sizes, int n_in,
                              void* d_out, int out_size, void* d_ws, size_t ws_size,
                              hipStream_t stream) {
  const float* X     = (const float*)d_in[0];
  const float* W1    = (const float*)d_in[1];
  const float* b1    = (const float*)d_in[2];
  const float* W2    = (const float*)d_in[3];
  const float* b2    = (const float*)d_in[4];
  const float* gamma = (const float*)d_in[5];
  const float* beta  = (const float*)d_in[6];
  float* Out = (float*)d_out;

  const size_t MB8 = (size_t)4 * 1048576;        // 4M bf16 elems = 8 MB
  bf16* W1P = (bf16*)d_ws;                       // 8 MB
  bf16* W2P = W1P + MB8;                         // 8 MB
  bf16* H   = W2P + MB8;                         // 8 MB
  bf16* Y0b = H + MB8;                           // 134 MB
  bf16* Xbf = Y0b + (size_t)4096 * 16384;        // 134 MB

  const size_t bigN = (size_t)4096 * 16384 * 2;  // 134,217,728 B
  const size_t base = 3 * (MB8 * 2);             // 25,165,824 B
  const int useBf = (ws_size >= base + bigN) ? 1 : 0;
  const int useXb = (ws_size >= base + 2 * bigN) ? 1 : 0;

  pack_w1<<<dim3(4, 128, 4), dim3(256), 0, stream>>>(W1, W1P);
  pack_w2<<<dim3(8, 16, 4), dim3(256), 0, stream>>>(W2, W2P);
  attn_kernel<<<dim3(4096), dim3(256), 0, stream>>>(X, Out, Y0b, Xbf, useBf, useXb);
  if (useXb)
    gemm1_kernel<1><<<dim3(256), dim3(512), 0, stream>>>(X, Xbf, W1P, b1, H);
  else
    gemm1_kernel<0><<<dim3(256), dim3(512), 0, stream>>>(X, Xbf, W1P, b1, H);
  gemm2_kernel<<<dim3(4096), dim3(256), 0, stream>>>(H, W2P, b2, gamma, beta,
                                                     Out, Y0b, useBf, Out);
}

// Round 5
// 442.143 us; speedup vs baseline: 1.7008x; 1.0191x over previous
//
#include <hip/hip_runtime.h>

// GlobalInteraction: B=4096, N_GLOBAL=64, D=256, E=4, TPE=16, F=TPE*D=4096
// X:(B,64,256) f32; W1:(E,4096,256); b1:(E,256); W2:(E,256,4096); b2:(E,4096);
// gamma,beta:(E,256). Out:(B,64,256) f32.
//
// Weights pre-packed into MFMA B-fragment order (64 lanes x 8 bf16 = 1KB per
// 16n x 32k fragment) -> coalesced B loads, no B LDS staging. gemm2: long
// blocks (4 t's each), Y0 reg-prefetch, LDS-transposed epilogue for dense
// Y0/Out access and cheap LN reduction.

typedef __attribute__((ext_vector_type(4))) float f32x4;
typedef __bf16 bf16;
typedef __attribute__((ext_vector_type(8))) bf16 bf16x8;

#define DEV static __device__ __forceinline__

DEV f32x4 zero4() { return f32x4{0.f, 0.f, 0.f, 0.f}; }

DEV bf16x8 cvt8(const f32x4& a, const f32x4& b) {
  bf16x8 o;
  o[0] = (bf16)a.x; o[1] = (bf16)a.y; o[2] = (bf16)a.z; o[3] = (bf16)a.w;
  o[4] = (bf16)b.x; o[5] = (bf16)b.y; o[6] = (bf16)b.z; o[7] = (bf16)b.w;
  return o;
}

// ---------------------------------------------------------------------------
// pack_w1: W1 (E,4096,256) f32 -> fragment-packed bf16.
// Frag (kc,nf): lane l, elem j = W1[e][kc*32+(l>>4)*8+j][nf*16+(l&15)]
// offset = ((e*128+kc)*16+nf)*512 + l*8
// ---------------------------------------------------------------------------
__global__ __launch_bounds__(256) void pack_w1(const float* __restrict__ W1,
                                               bf16* __restrict__ P) {
  const int e = blockIdx.z, kc = blockIdx.y;
  const int nf = blockIdx.x * 4 + (threadIdx.x >> 6);
  const int l = threadIdx.x & 63;
  const float* src = W1 + (size_t)e * 4096 * 256 +
                     (size_t)(kc * 32 + (l >> 4) * 8) * 256 + nf * 16 + (l & 15);
  bf16x8 o;
#pragma unroll
  for (int j = 0; j < 8; j++) o[j] = (bf16)src[(size_t)j * 256];
  *(bf16x8*)&P[(((size_t)e * 128 + kc) * 16 + nf) * 512 + l * 8] = o;
}

// ---------------------------------------------------------------------------
// pack_w2: W2 (E,256,4096) f32 -> fragment-packed bf16.
// Frag (t,nfl,kc): lane l, j = W2[e][kc*32+(l>>4)*8+j][t*256+nfl*16+(l&15)]
// offset = ((e*256 + t*16 + nfl)*8 + kc)*512 + l*8
// ---------------------------------------------------------------------------
__global__ __launch_bounds__(256) void pack_w2(const float* __restrict__ W2,
                                               bf16* __restrict__ P) {
  const int e = blockIdx.z, t = blockIdx.y, kc = blockIdx.x;
  const int l = threadIdx.x & 63;
#pragma unroll
  for (int it = 0; it < 4; it++) {
    int nfl = it * 4 + (threadIdx.x >> 6);
    const float* src = W2 + (size_t)e * 256 * 4096 +
                       (size_t)(kc * 32 + (l >> 4) * 8) * 4096 + t * 256 +
                       nfl * 16 + (l & 15);
    bf16x8 o;
#pragma unroll
    for (int j = 0; j < 8; j++) o[j] = (bf16)src[(size_t)j * 4096];
    *(bf16x8*)&P[(((size_t)e * 256 + t * 16 + nfl) * 8 + kc) * 512 + l * 8] = o;
  }
}

// ---------------------------------------------------------------------------
// attn: per (b,e): Y0 = softmax(Xp Xp^T / 16) Xp + Xp. One wave per pair.
// Also emits Xbf (bf16 cast of X) when useXb, for gemm1's A-staging.
// ---------------------------------------------------------------------------
__global__ __launch_bounds__(256) void attn_kernel(const float* __restrict__ X,
                                                   float* __restrict__ Y0f,
                                                   bf16* __restrict__ Y0b,
                                                   bf16* __restrict__ Xbf,
                                                   int useBf, int useXb) {
  // XpT: [d=256][tok=16] stride 16 (+pad); reused post-PV as Yl[16][264]
  __shared__ __align__(16) bf16 XpT[4][4224];
  __shared__ __align__(16) bf16 Pl[4][512];
  const int tid = threadIdx.x, lane = tid & 63, w = tid >> 6;
  const int lr = lane & 15, g = lane >> 4;
  bf16* xt = XpT[w];
  bf16* pl = Pl[w];

  for (int q = lane; q < 256; q += 64) {  // P cols 16..31 zero
    int row = q >> 4, cc = q & 15;
    pl[row * 32 + 16 + cc] = (bf16)0.f;
  }
  xt[4096 + lane] = (bf16)0.f;  // zero pad region [4096,4160)

  const int p = blockIdx.x * 4 + w;
  const int b = p >> 2, e = p & 3;
  const size_t obase0 = (size_t)b * 16384 + e * 4096;
  const float* Xb = X + obase0;

  bf16x8 af[8];
#pragma unroll
  for (int c = 0; c < 8; c++) {
    const float* q = Xb + lr * 256 + c * 32 + g * 8;
    f32x4 v0 = *(const f32x4*)q;
    f32x4 v1 = *(const f32x4*)(q + 4);
    bf16x8 o = cvt8(v0, v1);
    af[c] = o;
#pragma unroll
    for (int j = 0; j < 8; j++)
      xt[(c * 32 + g * 8 + j) * 16 + lr] = o[j];
    if (useXb) *(bf16x8*)&Xbf[obase0 + lr * 256 + c * 32 + g * 8] = o;
  }

  f32x4 s = zero4();
#pragma unroll
  for (int c = 0; c < 8; c++)
    s = __builtin_amdgcn_mfma_f32_16x16x32_bf16(af[c], af[c], s, 0, 0, 0);

  float pv[4];
#pragma unroll
  for (int r = 0; r < 4; r++) {
    float v = s[r] * 0.0625f;
    float mx = v;
#pragma unroll
    for (int m = 1; m < 16; m <<= 1) mx = fmaxf(mx, __shfl_xor(mx, m));
    float ev = __expf(v - mx);
    float sum = ev;
#pragma unroll
    for (int m = 1; m < 16; m <<= 1) sum += __shfl_xor(sum, m);
    pv[r] = ev / sum;
  }
#pragma unroll
  for (int r = 0; r < 4; r++) pl[(g * 4 + r) * 32 + lr] = (bf16)pv[r];

  bf16x8 pf = *(const bf16x8*)&pl[lr * 32 + g * 8];

  // PV: accumulate X_dot + Xp in registers (lane: tok=g*4+r, d=nc*16+lr)
  float yo[16][4];
#pragma unroll
  for (int nc = 0; nc < 16; nc++) {
    bf16x8 bfr = *(const bf16x8*)&xt[(nc * 16 + lr) * 16 + g * 8];
    f32x4 xd = __builtin_amdgcn_mfma_f32_16x16x32_bf16(pf, bfr, zero4(), 0, 0, 0);
#pragma unroll
    for (int r = 0; r < 4; r++)
      yo[nc][r] = xd[r] + (float)xt[(nc * 16 + lr) * 16 + g * 4 + r];
  }

  // transpose via LDS: Yl[tok][264] overlays xt (all xt reads complete; same
  // wave -> lgkmcnt orders the aliasing)
#pragma unroll
  for (int nc = 0; nc < 16; nc++)
#pragma unroll
    for (int r = 0; r < 4; r++)
      xt[(g * 4 + r) * 264 + nc * 16 + lr] = (bf16)yo[nc][r];

  // coalesced store: instr i writes 16 full 64B lines
  const int tok = lane >> 2, cc = lane & 3;
  if (useBf) {
#pragma unroll
    for (int i = 0; i < 8; i++) {
      int d0 = i * 32 + cc * 8;
      bf16x8 v = *(const bf16x8*)&xt[tok * 264 + d0];
      *(bf16x8*)&Y0b[obase0 + tok * 256 + d0] = v;
    }
  } else {
#pragma unroll
    for (int i = 0; i < 8; i++) {
      int d0 = i * 32 + cc * 8;
      bf16x8 v = *(const bf16x8*)&xt[tok * 264 + d0];
      f32x4 a, bb;
      a.x = (float)v[0]; a.y = (float)v[1]; a.z = (float)v[2]; a.w = (float)v[3];
      bb.x = (float)v[4]; bb.y = (float)v[5]; bb.z = (float)v[6]; bb.w = (float)v[7];
      *(f32x4*)&Y0f[obase0 + tok * 256 + d0] = a;
      *(f32x4*)&Y0f[obase0 + tok * 256 + d0 + 4] = bb;
    }
  }
}

// ---------------------------------------------------------------------------
// gemm1: H = relu(Xf @ W1[e] + b1[e]).  M-tile 64, N=256, K=4096, BK=128.
// 512 thr (8 waves = 2m x 4n). A reg-staged into padded dbuf LDS; B from
// packed fragments (coalesced global, no LDS).
// ---------------------------------------------------------------------------
template <int USEXBF>
__global__ __launch_bounds__(512) void gemm1_kernel(
    const float* __restrict__ X, const bf16* __restrict__ Xbf,
    const bf16* __restrict__ W1P, const float* __restrict__ b1,
    bf16* __restrict__ H) {
  __shared__ __align__(16) bf16 Ab[2][64 * 136];  // [64 rows][128+8 k]
  const int fid = blockIdx.x;                     // e -> XCD-pair swizzle
  const int e = (fid & 7) >> 1;
  const int m = ((fid >> 3) << 1) | (fid & 1);    // 0..63
  const int b0 = m * 64;
  const int tid = threadIdx.x, lane = tid & 63, w = tid >> 6;
  const int wm = w >> 2, wn = w & 3;
  const int lr = lane & 15, g = lane >> 4;

  const int arow = tid >> 3, ak0 = (tid & 7) * 16;
  const size_t abase = (size_t)(b0 + arow) * 16384 + e * 4096 + ak0;
  const bf16* Wp = W1P + (size_t)e * 128 * 16 * 512;

  f32x4 acc[2][4];
#pragma unroll
  for (int i = 0; i < 2; i++)
#pragma unroll
    for (int j = 0; j < 4; j++) acc[i][j] = zero4();

  f32x4 p0, p1, p2, p3;
  bf16x8 q0, q1;
  if (USEXBF) {
    q0 = *(const bf16x8*)&Xbf[abase];
    q1 = *(const bf16x8*)&Xbf[abase + 8];
  } else {
    const float* q = X + abase;
    p0 = *(const f32x4*)q;       p1 = *(const f32x4*)(q + 4);
    p2 = *(const f32x4*)(q + 8); p3 = *(const f32x4*)(q + 12);
  }

  for (int kt = 0; kt < 32; kt++) {
    const int cur = kt & 1;
    if (USEXBF) {
      *(bf16x8*)&Ab[cur][arow * 136 + ak0] = q0;
      *(bf16x8*)&Ab[cur][arow * 136 + ak0 + 8] = q1;
      if (kt < 31) {
        q0 = *(const bf16x8*)&Xbf[abase + (kt + 1) * 128];
        q1 = *(const bf16x8*)&Xbf[abase + (kt + 1) * 128 + 8];
      }
    } else {
      *(bf16x8*)&Ab[cur][arow * 136 + ak0] = cvt8(p0, p1);
      *(bf16x8*)&Ab[cur][arow * 136 + ak0 + 8] = cvt8(p2, p3);
      if (kt < 31) {
        const float* q = X + abase + (kt + 1) * 128;
        p0 = *(const f32x4*)q;       p1 = *(const f32x4*)(q + 4);
        p2 = *(const f32x4*)(q + 8); p3 = *(const f32x4*)(q + 12);
      }
    }
    __syncthreads();
#pragma unroll
    for (int kki = 0; kki < 4; kki++) {
      const int kc = kt * 4 + kki;
      bf16x8 afr[2], bfr[4];
#pragma unroll
      for (int i = 0; i < 2; i++)
        afr[i] = *(const bf16x8*)&Ab[cur][(wm * 32 + i * 16 + lr) * 136 +
                                          kki * 32 + g * 8];
#pragma unroll
      for (int j = 0; j < 4; j++)
        bfr[j] = *(const bf16x8*)&Wp[(((size_t)kc) * 16 + wn * 4 + j) * 512 +
                                     lane * 8];
#pragma unroll
      for (int i = 0; i < 2; i++)
#pragma unroll
        for (int j = 0; j < 4; j++)
          acc[i][j] = __builtin_amdgcn_mfma_f32_16x16x32_bf16(afr[i], bfr[j],
                                                              acc[i][j], 0, 0, 0);
    }
  }
#pragma unroll
  for (int j = 0; j < 4; j++) {
    int col = wn * 64 + j * 16 + lr;
    float bv = b1[e * 256 + col];
#pragma unroll
    for (int i = 0; i < 2; i++)
#pragma unroll
      for (int r = 0; r < 4; r++) {
        int row = wm * 32 + i * 16 + g * 4 + r;
        float v = fmaxf(acc[i][j][r] + bv, 0.f);
        H[((size_t)(b0 + row) * 4 + e) * 256 + col] = (bf16)v;
      }
  }
}

// ---------------------------------------------------------------------------
// gemm2: X_deep = H @ W2[e] + b2; Y = Y0 + X_deep; LayerNorm -> Out (f32).
// Block = (m-tile 64, e, t-quad): loops 4 t's. H staged once; per t: Y0
// reg-prefetch -> MFMA (B packed global) -> acc+b2 transposed to LDS (bf16)
// -> row-chunk epilogue: dense Y0 consume, 2-stage LN shuffle, f32x4 stores.
// ---------------------------------------------------------------------------
__global__ __launch_bounds__(256) void gemm2_kernel(
    const bf16* __restrict__ H, const bf16* __restrict__ W2P,
    const float* __restrict__ b2, const float* __restrict__ gamma,
    const float* __restrict__ beta, const float* __restrict__ Y0f,
    const bf16* __restrict__ Y0b, int useBf, float* __restrict__ Out) {
  __shared__ __align__(16) bf16 Ah[64 * 264];  // H tile
  __shared__ __align__(16) bf16 T[64 * 264];   // transposed X_deep+b2
  const int fid = blockIdx.x;
  const int e = fid & 3;            // e -> XCD (each XCD's L2 holds one W2 slice)
  const int rest = fid >> 2;        // 0..255
  const int tq = rest & 3;          // t-quad
  const int m = rest >> 2;          // 0..63
  const int b0 = m * 64;
  const int tid = threadIdx.x, lane = tid & 63, w = tid >> 6;
  const int lr = lane & 15, g = lane >> 4;
  const int erow = tid >> 2, ec = tid & 3;   // epilogue mapping

  // stage H tile (64 x 256 bf16), coalesced
#pragma unroll
  for (int i = 0; i < 8; i++) {
    int u = i * 256 + tid;
    int row = u >> 5, k8 = (u & 31) * 8;
    *(bf16x8*)&Ah[row * 264 + k8] =
        *(const bf16x8*)&H[((size_t)(b0 + row) * 4 + e) * 256 + k8];
  }
  __syncthreads();

  for (int tt = 0; tt < 4; tt++) {
    const int t = tq * 4 + tt;
    const size_t ebase = (size_t)(b0 + erow) * 16384 + e * 4096 + t * 256;

    // prefetch Y0 tile into regs (coalesced: 4 adjacent threads = 64B line)
    bf16x8 y0r[8];
    if (useBf) {
#pragma unroll
      for (int k = 0; k < 8; k++)
        y0r[k] = *(const bf16x8*)&Y0b[ebase + k * 32 + ec * 8];
    }

    // MFMA phase: 8 kc, A from LDS, B packed from global
    const bf16* Wp = W2P + (((size_t)e * 256 + t * 16 + w * 4) * 8) * 512;
    f32x4 acc[4][4];
#pragma unroll
    for (int i = 0; i < 4; i++)
#pragma unroll
      for (int j = 0; j < 4; j++) acc[i][j] = zero4();

#pragma unroll
    for (int kc = 0; kc < 8; kc++) {
      bf16x8 afr[4], bfr[4];
#pragma unroll
      for (int i = 0; i < 4; i++)
        afr[i] = *(const bf16x8*)&Ah[(i * 16 + lr) * 264 + kc * 32 + g * 8];
#pragma unroll
      for (int j = 0; j < 4; j++)
        bfr[j] = *(const bf16x8*)&Wp[((size_t)j * 8 + kc) * 512 + lane * 8];
#pragma unroll
      for (int i = 0; i < 4; i++)
#pragma unroll
        for (int j = 0; j < 4; j++)
          acc[i][j] = __builtin_amdgcn_mfma_f32_16x16x32_bf16(afr[i], bfr[j],
                                                              acc[i][j], 0, 0, 0);
    }

    float b2v[4];
#pragma unroll
    for (int j = 0; j < 4; j++)
      b2v[j] = b2[e * 4096 + t * 256 + w * 64 + j * 16 + lr];

    __syncthreads();  // prev epilogue's T reads done
    // write X_deep + b2 into T (MFMA-native orientation, scalar bf16)
#pragma unroll
    for (int i = 0; i < 4; i++)
#pragma unroll
      for (int j = 0; j < 4; j++)
#pragma unroll
        for (int r = 0; r < 4; r++)
          T[(i * 16 + g * 4 + r) * 264 + w * 64 + j * 16 + lr] =
              (bf16)(acc[i][j][r] + b2v[j]);
    __syncthreads();

    // epilogue: thread owns row erow, cols { k*32 + ec*8 + u }
    float y[8][8];
    float s1 = 0.f, s2 = 0.f;
#pragma unroll
    for (int k = 0; k < 8; k++) {
      bf16x8 tv = *(const bf16x8*)&T[erow * 264 + k * 32 + ec * 8];
      if (useBf) {
#pragma unroll
        for (int u = 0; u < 8; u++) {
          float v = (float)tv[u] + (float)y0r[k][u];
          y[k][u] = v;
          s1 += v;
          s2 += v * v;
        }
      } else {
        f32x4 a = *(const f32x4*)&Y0f[ebase + k * 32 + ec * 8];
        f32x4 bb = *(const f32x4*)&Y0f[ebase + k * 32 + ec * 8 + 4];
#pragma unroll
        for (int u = 0; u < 8; u++) {
          float v = (float)tv[u] + (u < 4 ? a[u] : bb[u - 4]);
          y[k][u] = v;
          s1 += v;
          s2 += v * v;
        }
      }
    }
    s1 += __shfl_xor(s1, 1); s1 += __shfl_xor(s1, 2);
    s2 += __shfl_xor(s2, 1); s2 += __shfl_xor(s2, 2);
    const float mu = s1 * (1.f / 256.f);
    const float var = s2 * (1.f / 256.f) - mu * mu;
    const float rs = rsqrtf(var + 1e-5f);

#pragma unroll
    for (int k = 0; k < 8; k++) {
      const int col = k * 32 + ec * 8;
      f32x4 gv0 = *(const f32x4*)&gamma[e * 256 + col];
      f32x4 gv1 = *(const f32x4*)&gamma[e * 256 + col + 4];
      f32x4 bt0 = *(const f32x4*)&beta[e * 256 + col];
      f32x4 bt1 = *(const f32x4*)&beta[e * 256 + col + 4];
      f32x4 o0, o1;
#pragma unroll
      for (int u = 0; u < 4; u++) {
        o0[u] = (y[k][u] - mu) * rs * gv0[u] + bt0[u];
        o1[u] = (y[k][u + 4] - mu) * rs * gv1[u] + bt1[u];
      }
      *(f32x4*)&Out[ebase + col] = o0;
      *(f32x4*)&Out[ebase + col + 4] = o1;
    }
  }
}

// ---------------------------------------------------------------------------
extern "C" void kernel_launch(void* const* d_in, const int* in_sizes, int n_in,
                              void* d_out, int out_size, void* d_ws, size_t ws_size,
                              hipStream_t stream) {
  const float* X     = (const float*)d_in[0];
  const float* W1    = (const float*)d_in[1];
  const float* b1    = (const float*)d_in[2];
  const float* W2    = (const float*)d_in[3];
  const float* b2    = (const float*)d_in[4];
  const float* gamma = (const float*)d_in[5];
  const float* beta  = (const float*)d_in[6];
  float* Out = (float*)d_out;

  const size_t MB8 = (size_t)4 * 1048576;        // 4M bf16 elems = 8 MB
  bf16* W1P = (bf16*)d_ws;                       // 8 MB
  bf16* W2P = W1P + MB8;                         // 8 MB
  bf16* H   = W2P + MB8;                         // 8 MB
  bf16* Y0b = H + MB8;                           // 134 MB
  bf16* Xbf = Y0b + (size_t)4096 * 16384;        // 134 MB

  const size_t bigN = (size_t)4096 * 16384 * 2;  // 134,217,728 B
  const size_t base = 3 * (MB8 * 2);             // 25,165,824 B
  const int useBf = (ws_size >= base + bigN) ? 1 : 0;
  const int useXb = (ws_size >= base + 2 * bigN) ? 1 : 0;

  pack_w1<<<dim3(4, 128, 4), dim3(256), 0, stream>>>(W1, W1P);
  pack_w2<<<dim3(8, 16, 4), dim3(256), 0, stream>>>(W2, W2P);
  attn_kernel<<<dim3(4096), dim3(256), 0, stream>>>(X, Out, Y0b, Xbf, useBf, useXb);
  if (useXb)
    gemm1_kernel<1><<<dim3(256), dim3(512), 0, stream>>>(X, Xbf, W1P, b1, H);
  else
    gemm1_kernel<0><<<dim3(256), dim3(512), 0, stream>>>(X, Xbf, W1P, b1, H);
  gemm2_kernel<<<dim3(1024), dim3(256), 0, stream>>>(H, W2P, b2, gamma, beta,
                                                     Out, Y0b, useBf, Out);
}

// Round 6
// 440.673 us; speedup vs baseline: 1.7064x; 1.0033x over previous
//
#include <hip/hip_runtime.h>

// GlobalInteraction: B=4096, N_GLOBAL=64, D=256, E=4, TPE=16, F=TPE*D=4096
// X:(B,64,256) f32; W1:(E,4096,256); b1:(E,256); W2:(E,256,4096); b2:(E,4096);
// gamma,beta:(E,256). Out:(B,64,256) f32.
//
// All GEMM operands fragment-packed (64 lanes x 8 bf16 = 1KB per 16x32 frag).
// gemm2 r6: block = (e,t); W2 B-frags live in REGISTERS for the whole block
// (no per-kc global B loads); loop over 8 m-tiles with A from packed HP
// (L2-resident, coalesced); T-transpose epilogue + fused LayerNorm.

typedef __attribute__((ext_vector_type(4))) float f32x4;
typedef __bf16 bf16;
typedef __attribute__((ext_vector_type(8))) bf16 bf16x8;

#define DEV static __device__ __forceinline__

DEV f32x4 zero4() { return f32x4{0.f, 0.f, 0.f, 0.f}; }

DEV bf16x8 cvt8(const f32x4& a, const f32x4& b) {
  bf16x8 o;
  o[0] = (bf16)a.x; o[1] = (bf16)a.y; o[2] = (bf16)a.z; o[3] = (bf16)a.w;
  o[4] = (bf16)b.x; o[5] = (bf16)b.y; o[6] = (bf16)b.z; o[7] = (bf16)b.w;
  return o;
}

// ---------------------------------------------------------------------------
// pack_w1: W1 (E,4096,256) f32 -> fragment-packed bf16.
// Frag (kc,nf): lane l, elem j = W1[e][kc*32+(l>>4)*8+j][nf*16+(l&15)]
// ---------------------------------------------------------------------------
__global__ __launch_bounds__(256) void pack_w1(const float* __restrict__ W1,
                                               bf16* __restrict__ P) {
  const int e = blockIdx.z, kc = blockIdx.y;
  const int nf = blockIdx.x * 4 + (threadIdx.x >> 6);
  const int l = threadIdx.x & 63;
  const float* src = W1 + (size_t)e * 4096 * 256 +
                     (size_t)(kc * 32 + (l >> 4) * 8) * 256 + nf * 16 + (l & 15);
  bf16x8 o;
#pragma unroll
  for (int j = 0; j < 8; j++) o[j] = (bf16)src[(size_t)j * 256];
  *(bf16x8*)&P[(((size_t)e * 128 + kc) * 16 + nf) * 512 + l * 8] = o;
}

// ---------------------------------------------------------------------------
// pack_w2: W2 (E,256,4096) f32 -> fragment-packed bf16.
// Frag (t,nfl,kc): lane l, j = W2[e][kc*32+(l>>4)*8+j][t*256+nfl*16+(l&15)]
// ---------------------------------------------------------------------------
__global__ __launch_bounds__(256) void pack_w2(const float* __restrict__ W2,
                                               bf16* __restrict__ P) {
  const int e = blockIdx.z, t = blockIdx.y, kc = blockIdx.x;
  const int l = threadIdx.x & 63;
#pragma unroll
  for (int it = 0; it < 4; it++) {
    int nfl = it * 4 + (threadIdx.x >> 6);
    const float* src = W2 + (size_t)e * 256 * 4096 +
                       (size_t)(kc * 32 + (l >> 4) * 8) * 4096 + t * 256 +
                       nfl * 16 + (l & 15);
    bf16x8 o;
#pragma unroll
    for (int j = 0; j < 8; j++) o[j] = (bf16)src[(size_t)j * 4096];
    *(bf16x8*)&P[(((size_t)e * 256 + t * 16 + nfl) * 8 + kc) * 512 + l * 8] = o;
  }
}

// ---------------------------------------------------------------------------
// attn: per (b,e): Y0 = softmax(Xp Xp^T / 16) Xp + Xp. One wave per pair.
// Also emits Xbf (bf16 cast of X) when useXb, for gemm1's A-staging.
// ---------------------------------------------------------------------------
__global__ __launch_bounds__(256) void attn_kernel(const float* __restrict__ X,
                                                   float* __restrict__ Y0f,
                                                   bf16* __restrict__ Y0b,
                                                   bf16* __restrict__ Xbf,
                                                   int useBf, int useXb) {
  __shared__ __align__(16) bf16 XpT[4][4224];
  __shared__ __align__(16) bf16 Pl[4][512];
  const int tid = threadIdx.x, lane = tid & 63, w = tid >> 6;
  const int lr = lane & 15, g = lane >> 4;
  bf16* xt = XpT[w];
  bf16* pl = Pl[w];

  for (int q = lane; q < 256; q += 64) {
    int row = q >> 4, cc = q & 15;
    pl[row * 32 + 16 + cc] = (bf16)0.f;
  }
  xt[4096 + lane] = (bf16)0.f;

  const int p = blockIdx.x * 4 + w;
  const int b = p >> 2, e = p & 3;
  const size_t obase0 = (size_t)b * 16384 + e * 4096;
  const float* Xb = X + obase0;

  bf16x8 af[8];
#pragma unroll
  for (int c = 0; c < 8; c++) {
    const float* q = Xb + lr * 256 + c * 32 + g * 8;
    f32x4 v0 = *(const f32x4*)q;
    f32x4 v1 = *(const f32x4*)(q + 4);
    bf16x8 o = cvt8(v0, v1);
    af[c] = o;
#pragma unroll
    for (int j = 0; j < 8; j++)
      xt[(c * 32 + g * 8 + j) * 16 + lr] = o[j];
    if (useXb) *(bf16x8*)&Xbf[obase0 + lr * 256 + c * 32 + g * 8] = o;
  }

  f32x4 s = zero4();
#pragma unroll
  for (int c = 0; c < 8; c++)
    s = __builtin_amdgcn_mfma_f32_16x16x32_bf16(af[c], af[c], s, 0, 0, 0);

  float pv[4];
#pragma unroll
  for (int r = 0; r < 4; r++) {
    float v = s[r] * 0.0625f;
    float mx = v;
#pragma unroll
    for (int m = 1; m < 16; m <<= 1) mx = fmaxf(mx, __shfl_xor(mx, m));
    float ev = __expf(v - mx);
    float sum = ev;
#pragma unroll
    for (int m = 1; m < 16; m <<= 1) sum += __shfl_xor(sum, m);
    pv[r] = ev / sum;
  }
#pragma unroll
  for (int r = 0; r < 4; r++) pl[(g * 4 + r) * 32 + lr] = (bf16)pv[r];

  bf16x8 pf = *(const bf16x8*)&pl[lr * 32 + g * 8];

  float yo[16][4];
#pragma unroll
  for (int nc = 0; nc < 16; nc++) {
    bf16x8 bfr = *(const bf16x8*)&xt[(nc * 16 + lr) * 16 + g * 8];
    f32x4 xd = __builtin_amdgcn_mfma_f32_16x16x32_bf16(pf, bfr, zero4(), 0, 0, 0);
#pragma unroll
    for (int r = 0; r < 4; r++)
      yo[nc][r] = xd[r] + (float)xt[(nc * 16 + lr) * 16 + g * 4 + r];
  }

#pragma unroll
  for (int nc = 0; nc < 16; nc++)
#pragma unroll
    for (int r = 0; r < 4; r++)
      xt[(g * 4 + r) * 264 + nc * 16 + lr] = (bf16)yo[nc][r];

  const int tok = lane >> 2, cc = lane & 3;
  if (useBf) {
#pragma unroll
    for (int i = 0; i < 8; i++) {
      int d0 = i * 32 + cc * 8;
      bf16x8 v = *(const bf16x8*)&xt[tok * 264 + d0];
      *(bf16x8*)&Y0b[obase0 + tok * 256 + d0] = v;
    }
  } else {
#pragma unroll
    for (int i = 0; i < 8; i++) {
      int d0 = i * 32 + cc * 8;
      bf16x8 v = *(const bf16x8*)&xt[tok * 264 + d0];
      f32x4 a, bb;
      a.x = (float)v[0]; a.y = (float)v[1]; a.z = (float)v[2]; a.w = (float)v[3];
      bb.x = (float)v[4]; bb.y = (float)v[5]; bb.z = (float)v[6]; bb.w = (float)v[7];
      *(f32x4*)&Y0f[obase0 + tok * 256 + d0] = a;
      *(f32x4*)&Y0f[obase0 + tok * 256 + d0 + 4] = bb;
    }
  }
}

// ---------------------------------------------------------------------------
// gemm1: H = relu(Xf @ W1[e] + b1[e]).  M-tile 64, N=256, K=4096, BK=128.
// Epilogue writes HP in A-fragment-packed order for gemm2:
// HP[((e*256+mfg)*8+kc)*512 + l*8 + jj] = H[row=mfg*16+(l&15)][k=kc*32+(l>>4)*8+jj]
// ---------------------------------------------------------------------------
template <int USEXBF>
__global__ __launch_bounds__(512) void gemm1_kernel(
    const float* __restrict__ X, const bf16* __restrict__ Xbf,
    const bf16* __restrict__ W1P, const float* __restrict__ b1,
    bf16* __restrict__ HP) {
  __shared__ __align__(16) bf16 Ab[2][64 * 136];
  const int fid = blockIdx.x;
  const int e = (fid & 7) >> 1;
  const int m = ((fid >> 3) << 1) | (fid & 1);    // 0..63
  const int b0 = m * 64;
  const int tid = threadIdx.x, lane = tid & 63, w = tid >> 6;
  const int wm = w >> 2, wn = w & 3;
  const int lr = lane & 15, g = lane >> 4;

  const int arow = tid >> 3, ak0 = (tid & 7) * 16;
  const size_t abase = (size_t)(b0 + arow) * 16384 + e * 4096 + ak0;
  const bf16* Wp = W1P + (size_t)e * 128 * 16 * 512;

  f32x4 acc[2][4];
#pragma unroll
  for (int i = 0; i < 2; i++)
#pragma unroll
    for (int j = 0; j < 4; j++) acc[i][j] = zero4();

  f32x4 p0, p1, p2, p3;
  bf16x8 q0, q1;
  if (USEXBF) {
    q0 = *(const bf16x8*)&Xbf[abase];
    q1 = *(const bf16x8*)&Xbf[abase + 8];
  } else {
    const float* q = X + abase;
    p0 = *(const f32x4*)q;       p1 = *(const f32x4*)(q + 4);
    p2 = *(const f32x4*)(q + 8); p3 = *(const f32x4*)(q + 12);
  }

  for (int kt = 0; kt < 32; kt++) {
    const int cur = kt & 1;
    if (USEXBF) {
      *(bf16x8*)&Ab[cur][arow * 136 + ak0] = q0;
      *(bf16x8*)&Ab[cur][arow * 136 + ak0 + 8] = q1;
      if (kt < 31) {
        q0 = *(const bf16x8*)&Xbf[abase + (kt + 1) * 128];
        q1 = *(const bf16x8*)&Xbf[abase + (kt + 1) * 128 + 8];
      }
    } else {
      *(bf16x8*)&Ab[cur][arow * 136 + ak0] = cvt8(p0, p1);
      *(bf16x8*)&Ab[cur][arow * 136 + ak0 + 8] = cvt8(p2, p3);
      if (kt < 31) {
        const float* q = X + abase + (kt + 1) * 128;
        p0 = *(const f32x4*)q;       p1 = *(const f32x4*)(q + 4);
        p2 = *(const f32x4*)(q + 8); p3 = *(const f32x4*)(q + 12);
      }
    }
    __syncthreads();
#pragma unroll
    for (int kki = 0; kki < 4; kki++) {
      const int kc = kt * 4 + kki;
      bf16x8 afr[2], bfr[4];
#pragma unroll
      for (int i = 0; i < 2; i++)
        afr[i] = *(const bf16x8*)&Ab[cur][(wm * 32 + i * 16 + lr) * 136 +
                                          kki * 32 + g * 8];
#pragma unroll
      for (int j = 0; j < 4; j++)
        bfr[j] = *(const bf16x8*)&Wp[(((size_t)kc) * 16 + wn * 4 + j) * 512 +
                                     lane * 8];
#pragma unroll
      for (int i = 0; i < 2; i++)
#pragma unroll
        for (int j = 0; j < 4; j++)
          acc[i][j] = __builtin_amdgcn_mfma_f32_16x16x32_bf16(afr[i], bfr[j],
                                                              acc[i][j], 0, 0, 0);
    }
    __syncthreads();
  }
  // epilogue: relu(acc + b1) -> HP (fragment-packed)
#pragma unroll
  for (int j = 0; j < 4; j++) {
    const int col = wn * 64 + j * 16 + lr;
    const float bv = b1[e * 256 + col];
    const int kc = col >> 5, lhi = (col >> 3) & 3, jj = col & 7;
#pragma unroll
    for (int i = 0; i < 2; i++) {
      const int mfg = m * 4 + wm * 2 + i;
      bf16* dst = HP + (((size_t)e * 256 + mfg) * 8 + kc) * 512 + jj;
#pragma unroll
      for (int r = 0; r < 4; r++) {
        float v = fmaxf(acc[i][j][r] + bv, 0.f);
        dst[(lhi * 16 + g * 4 + r) * 8] = (bf16)v;
      }
    }
  }
}

// ---------------------------------------------------------------------------
// gemm2 r6: block = (e, t, m-split). 512 thr = 8 waves x 32 n-cols.
// W2 B-frags (16 x 1KB per wave) loaded ONCE into registers; loop 8 m-tiles:
// A-frags from packed HP (coalesced, L2-resident), 1-deep kc pipeline,
// zero global loads for B in the loop. T-transpose epilogue + fused LN.
// ---------------------------------------------------------------------------
__global__ __launch_bounds__(512) void gemm2_kernel(
    const bf16* __restrict__ HP, const bf16* __restrict__ W2P,
    const float* __restrict__ b2, const float* __restrict__ gamma,
    const float* __restrict__ beta, const float* __restrict__ Y0f,
    const bf16* __restrict__ Y0b, int useBf, float* __restrict__ Out) {
  __shared__ __align__(16) bf16 T[64 * 264];
  const int fid = blockIdx.x;
  const int e = fid & 3;          // e pinned per XCD (blockIdx%8 round-robin)
  const int rr_ = fid >> 2;       // 0..127
  const int t = rr_ & 15;
  const int ms = rr_ >> 4;        // 0..7
  const int tid = threadIdx.x, lane = tid & 63, w = tid >> 6;  // w 0..7
  const int lr = lane & 15, g = lane >> 4;
  const int erow = tid >> 3, ec = tid & 7;

  // resident B: wave w owns cols [w*32, w*32+32), nfl = w*2+nj
  bf16x8 breg[2][8];
  {
    const bf16* Wp = W2P + (((size_t)e * 256 + t * 16 + w * 2) * 8) * 512 +
                     lane * 8;
#pragma unroll
    for (int nj = 0; nj < 2; nj++)
#pragma unroll
      for (int kc = 0; kc < 8; kc++)
        breg[nj][kc] = *(const bf16x8*)&Wp[(size_t)(nj * 8 + kc) * 512];
  }
  float b2v[2];
#pragma unroll
  for (int nj = 0; nj < 2; nj++)
    b2v[nj] = b2[e * 4096 + t * 256 + w * 32 + nj * 16 + lr];

  for (int it = 0; it < 8; it++) {
    const int mt = ms * 8 + it;
    const int b0 = mt * 64;
    const size_t ebase =
        (size_t)(b0 + erow) * 16384 + e * 4096 + t * 256 + ec * 32;

    // Y0 prefetch (overlaps MFMA phase)
    bf16x8 y0r[4];
    if (useBf) {
#pragma unroll
      for (int u = 0; u < 4; u++)
        y0r[u] = *(const bf16x8*)&Y0b[ebase + u * 8];
    }

    // MFMA: A from HP, 1-deep kc pipeline
    const bf16* Ap = HP + (((size_t)e * 256 + mt * 4) * 8) * 512 + lane * 8;
    f32x4 acc[4][2];
#pragma unroll
    for (int mf = 0; mf < 4; mf++)
#pragma unroll
      for (int nj = 0; nj < 2; nj++) acc[mf][nj] = zero4();

    bf16x8 afr[4], afn[4];
#pragma unroll
    for (int mf = 0; mf < 4; mf++)
      afr[mf] = *(const bf16x8*)&Ap[(size_t)(mf * 8) * 512];
#pragma unroll
    for (int kc = 0; kc < 8; kc++) {
      if (kc < 7) {
#pragma unroll
        for (int mf = 0; mf < 4; mf++)
          afn[mf] = *(const bf16x8*)&Ap[(size_t)(mf * 8 + kc + 1) * 512];
      }
#pragma unroll
      for (int mf = 0; mf < 4; mf++)
#pragma unroll
        for (int nj = 0; nj < 2; nj++)
          acc[mf][nj] = __builtin_amdgcn_mfma_f32_16x16x32_bf16(
              afr[mf], breg[nj][kc], acc[mf][nj], 0, 0, 0);
#pragma unroll
      for (int mf = 0; mf < 4; mf++) afr[mf] = afn[mf];
    }

    __syncthreads();  // prior epilogue's T reads complete
#pragma unroll
    for (int mf = 0; mf < 4; mf++)
#pragma unroll
      for (int nj = 0; nj < 2; nj++)
#pragma unroll
        for (int r = 0; r < 4; r++)
          T[(mf * 16 + g * 4 + r) * 264 + w * 32 + nj * 16 + lr] =
              (bf16)(acc[mf][nj][r] + b2v[nj]);
    __syncthreads();

    // epilogue: thread owns row erow, cols [ec*32, ec*32+32)
    float y[4][8];
    float s1 = 0.f, s2 = 0.f;
#pragma unroll
    for (int u = 0; u < 4; u++) {
      bf16x8 tv = *(const bf16x8*)&T[erow * 264 + ec * 32 + u * 8];
      if (useBf) {
#pragma unroll
        for (int u8 = 0; u8 < 8; u8++) {
          float v = (float)tv[u8] + (float)y0r[u][u8];
          y[u][u8] = v;
          s1 += v;
          s2 += v * v;
        }
      } else {
        f32x4 a = *(const f32x4*)&Y0f[ebase + u * 8];
        f32x4 bb = *(const f32x4*)&Y0f[ebase + u * 8 + 4];
#pragma unroll
        for (int u8 = 0; u8 < 8; u8++) {
          float v = (float)tv[u8] + (u8 < 4 ? a[u8] : bb[u8 - 4]);
          y[u][u8] = v;
          s1 += v;
          s2 += v * v;
        }
      }
    }
    s1 += __shfl_xor(s1, 1); s1 += __shfl_xor(s1, 2); s1 += __shfl_xor(s1, 4);
    s2 += __shfl_xor(s2, 1); s2 += __shfl_xor(s2, 2); s2 += __shfl_xor(s2, 4);
    const float mu = s1 * (1.f / 256.f);
    const float var = s2 * (1.f / 256.f) - mu * mu;
    const float rs = rsqrtf(var + 1e-5f);

#pragma unroll
    for (int u = 0; u < 4; u++) {
      const int col = ec * 32 + u * 8;
      f32x4 gv0 = *(const f32x4*)&gamma[e * 256 + col];
      f32x4 gv1 = *(const f32x4*)&gamma[e * 256 + col + 4];
      f32x4 bt0 = *(const f32x4*)&beta[e * 256 + col];
      f32x4 bt1 = *(const f32x4*)&beta[e * 256 + col + 4];
      f32x4 o0, o1;
#pragma unroll
      for (int u8 = 0; u8 < 4; u8++) {
        o0[u8] = (y[u][u8] - mu) * rs * gv0[u8] + bt0[u8];
        o1[u8] = (y[u][u8 + 4] - mu) * rs * gv1[u8] + bt1[u8];
      }
      *(f32x4*)&Out[ebase + u * 8] = o0;
      *(f32x4*)&Out[ebase + u * 8 + 4] = o1;
    }
  }
}

// ---------------------------------------------------------------------------
extern "C" void kernel_launch(void* const* d_in, const int* in_sizes, int n_in,
                              void* d_out, int out_size, void* d_ws, size_t ws_size,
                              hipStream_t stream) {
  const float* X     = (const float*)d_in[0];
  const float* W1    = (const float*)d_in[1];
  const float* b1    = (const float*)d_in[2];
  const float* W2    = (const float*)d_in[3];
  const float* b2    = (const float*)d_in[4];
  const float* gamma = (const float*)d_in[5];
  const float* beta  = (const float*)d_in[6];
  float* Out = (float*)d_out;

  const size_t MB8 = (size_t)4 * 1048576;        // 4M bf16 elems = 8 MB
  bf16* W1P = (bf16*)d_ws;                       // 8 MB
  bf16* W2P = W1P + MB8;                         // 8 MB
  bf16* HP  = W2P + MB8;                         // 8 MB (fragment-packed H)
  bf16* Y0b = HP + MB8;                          // 134 MB
  bf16* Xbf = Y0b + (size_t)4096 * 16384;        // 134 MB

  const size_t bigN = (size_t)4096 * 16384 * 2;  // 134,217,728 B
  const size_t base = 3 * (MB8 * 2);             // 25,165,824 B
  const int useBf = (ws_size >= base + bigN) ? 1 : 0;
  const int useXb = (ws_size >= base + 2 * bigN) ? 1 : 0;

  pack_w1<<<dim3(4, 128, 4), dim3(256), 0, stream>>>(W1, W1P);
  pack_w2<<<dim3(8, 16, 4), dim3(256), 0, stream>>>(W2, W2P);
  attn_kernel<<<dim3(4096), dim3(256), 0, stream>>>(X, Out, Y0b, Xbf, useBf, useXb);
  if (useXb)
    gemm1_kernel<1><<<dim3(256), dim3(512), 0, stream>>>(X, Xbf, W1P, b1, HP);
  else
    gemm1_kernel<0><<<dim3(256), dim3(512), 0, stream>>>(X, Xbf, W1P, b1, HP);
  gemm2_kernel<<<dim3(512), dim3(512), 0, stream>>>(HP, W2P, b2, gamma, beta,
                                                    Out, Y0b, useBf, Out);
}